// Round 6
// baseline (726.939 us; speedup 1.0000x reference)
//
#include <hip/hip_runtime.h>
#include <math.h>

// ---------------------------------------------------------------------------
// VQ-VAE forward.
// Encoder: 256-ch convs as implicit-GEMM MFMA with 2-term bf16 split inputs
// (3 passes: w1x1 + w1x2 + w2x1). Big convs: 64co x 128px blocks (round-4
// geometry, 512 blocks = 2/CU), split-K=2 into per-kz SLABS (plain stores,
// no atomics -- round 5 showed cross-XCD atomicAdd writes 10x the traffic),
// reduced in a fixed-order epilogue (deterministic).
// All MFMA LDS tiles pitch-40 ushorts (80 B): 16-lane phases are 2-way on
// banks (free, m136); round-4's pitch-32 was 8-way on fragment reads.
// VQ: chunk-parallel partial argmin + reduce; bit-identical to serial.
// Decoder: t1 + t2 plain bf16 MFMA (pitch-40).
// ---------------------------------------------------------------------------

typedef unsigned int uint;
typedef unsigned short ushort_t;
using short8 = __attribute__((ext_vector_type(8))) short;
using f32x4  = __attribute__((ext_vector_type(4))) float;

static __device__ __forceinline__ ushort_t f2bf(float f) {
  uint u = __float_as_uint(f);
  return (ushort_t)((u + 0x7fffu + ((u >> 16) & 1u)) >> 16);  // RNE; finite inputs
}
static __device__ __forceinline__ float bf2f(ushort_t b) {
  return __uint_as_float(((uint)b) << 16);
}

// ---------- weight prep ----------
__global__ void k_transpose_w(const float* __restrict__ w, float* __restrict__ wT, int CO, int CIKK) {
  int idx = blockIdx.x * 256 + threadIdx.x;
  if (idx >= CO * CIKK) return;
  int co = idx % CO, i = idx / CO;
  wT[idx] = w[co * CIKK + i];
}

// encoder MFMA weight pack: w[co][ci(256)][KH][KW] fp32 ->
// wp[chunk][coT(4)][pl(2)][row(64)][k(32)] bf16 split, chunk = tap*8 + cg
template<int KIND>  // 0: 4x4 (16 taps), 1: 3x3 (9 taps), 2: 1x1 (1 tap)
__global__ void k_prep_enc(const float* __restrict__ w, ushort_t* __restrict__ wp, int total) {
  int idx = blockIdx.x * 256 + threadIdx.x;
  if (idx >= total) return;
  int k = idx & 31, row = (idx >> 5) & 63, pl = (idx >> 11) & 1, coT = (idx >> 12) & 3, chunk = idx >> 14;
  int tap = chunk >> 3, cg = chunk & 7;
  int co = coT * 64 + row, ci = cg * 32 + k;
  int ky, kx, KK, KW;
  if (KIND == 0)      { ky = tap >> 2; kx = tap & 3;       KK = 16; KW = 4; }
  else if (KIND == 1) { ky = tap / 3;  kx = tap - ky * 3;  KK = 9;  KW = 3; }
  else                { ky = 0;        kx = 0;             KK = 1;  KW = 1; }
  float v = w[(co * 256 + ci) * KK + ky * KW + kx];
  ushort_t b0 = f2bf(v);
  wp[idx] = pl ? f2bf(v - bf2f(b0)) : b0;
}

// t1_w [ci][co][ky][kx] -> bf16 [par][tap][c8][co][kk32]
__global__ void k_prep_t1w(const float* __restrict__ w, ushort_t* __restrict__ wb) {
  int idx = blockIdx.x * 256 + threadIdx.x;  // 1048576
  int kk  = idx & 31;
  int co  = (idx >> 5) & 255;
  int c8  = (idx >> 13) & 7;
  int tap = (idx >> 16) & 3;
  int par = idx >> 18;
  int ry = par & 1, rx = (par >> 1) & 1;
  int a = tap >> 1, b = tap & 1;
  int ky = ((ry + 1) & 1) + 2 * a;
  int kx = ((rx + 1) & 1) + 2 * b;
  int ci = c8 * 32 + kk;
  wb[idx] = f2bf(w[((ci * 256 + co) << 4) + ky * 4 + kx]);
}

// t2_w [ci(256)][co(3)][4][4] -> bf16 [par(4)][chunk(32)][co16][k32]
__global__ void k_prep_t2w(const float* __restrict__ w, ushort_t* __restrict__ wb) {
  int idx = blockIdx.x * 256 + threadIdx.x;  // 65536
  int k = idx & 31, co = (idx >> 5) & 15, chunk = (idx >> 9) & 31, par = idx >> 14;
  int tap = chunk >> 3, cg = chunk & 7;
  int a = tap >> 1, b = tap & 1;
  int ry = par & 1, rx = (par >> 1) & 1;
  int ky = ((ry + 1) & 1) + 2 * a;
  int kx = ((rx + 1) & 1) + 2 * b;
  int ci = cg * 32 + k;
  float v = (co < 3) ? w[((ci * 3 + co) << 4) + ky * 4 + kx] : 0.f;
  wb[idx] = f2bf(v);
}

// cnorm[j] = sum_c cb[j][c]^2
__global__ void k_prep_cb(const float* __restrict__ cb, float* __restrict__ cnorm) {
  int idx = blockIdx.x * 256 + threadIdx.x;
  if (idx < 512) {
    float s = 0.f;
    for (int c = 0; c < 64; ++c) { float v = cb[idx * 64 + c]; s = fmaf(v, v, s); }
    cnorm[idx] = s;
  }
}

// ---------- conv1: 3->256, 4x4 s2 p1, relu, output split-bf16 NHWC ----------
__global__ __launch_bounds__(256) void k_conv1_split(
    const float* __restrict__ in, ushort_t* __restrict__ o0, ushort_t* __restrict__ o1,
    const float* __restrict__ wT, const float* __restrict__ bias)
{
  __shared__ float s_in[3 * 360];  // parity-split cols, pitch 20 (2-way free)
  const int tid = threadIdx.x;
  const int lane = tid & 63;
  const int wv = __builtin_amdgcn_readfirstlane(tid >> 6);
  const int px = lane & 7, py = lane >> 3;
  const int tx = blockIdx.x & 7, ty = blockIdx.x >> 3;
  const int X = tx * 8, Y = ty * 8;
  const int cob = blockIdx.y * 64 + wv * 16;
  const int n = blockIdx.z;
  float acc[16];
#pragma unroll
  for (int i = 0; i < 16; ++i) acc[i] = bias[cob + i];
  const float* inN = in + (size_t)n * 3 * 16384;
  for (int e = tid; e < 3 * 360; e += 256) {
    int col2 = e % 20; int t = e / 20; int row = t % 18; int ci = t / 18;
    int pr = col2 / 10, hc = col2 % 10, ixl = 2 * hc + pr;
    int iy = 2 * Y - 1 + row, ix = 2 * X - 1 + ixl;
    float v = 0.f;
    if (ixl < 18 && (unsigned)iy < 128u && (unsigned)ix < 128u)
      v = inN[ci * 16384 + iy * 128 + ix];
    s_in[e] = v;
  }
  __syncthreads();
  const float* wc = wT + cob;
#pragma unroll
  for (int c = 0; c < 3; ++c) {
    const float* base = s_in + c * 360 + py * 40 + px;
#pragma unroll
    for (int ky = 0; ky < 4; ++ky) {
#pragma unroll
      for (int kx = 0; kx < 4; ++kx) {
        float iv = base[ky * 20 + (kx & 1) * 10 + (kx >> 1)];
        const float* w = wc + (size_t)(c * 16 + ky * 4 + kx) * 256;  // uniform
#pragma unroll
        for (int i = 0; i < 16; ++i) acc[i] = fmaf(iv, w[i], acc[i]);
      }
    }
  }
  const int pxg = n * 4096 + (Y + py) * 64 + (X + px);
  uint p0[8], p1[8];
#pragma unroll
  for (int i = 0; i < 8; ++i) {
    float va = fmaxf(acc[2 * i], 0.f), vb = fmaxf(acc[2 * i + 1], 0.f);
    ushort_t a0 = f2bf(va), b0 = f2bf(vb);
    ushort_t a1 = f2bf(va - bf2f(a0)), b1 = f2bf(vb - bf2f(b0));
    p0[i] = (uint)a0 | ((uint)b0 << 16);
    p1[i] = (uint)a1 | ((uint)b1 << 16);
  }
  ushort_t* d0 = o0 + (size_t)pxg * 256 + cob;
  ushort_t* d1 = o1 + (size_t)pxg * 256 + cob;
  uint4 v0a; v0a.x = p0[0]; v0a.y = p0[1]; v0a.z = p0[2]; v0a.w = p0[3];
  uint4 v0b; v0b.x = p0[4]; v0b.y = p0[5]; v0b.z = p0[6]; v0b.w = p0[7];
  uint4 v1a; v1a.x = p1[0]; v1a.y = p1[1]; v1a.z = p1[2]; v1a.w = p1[3];
  uint4 v1b; v1b.x = p1[4]; v1b.y = p1[5]; v1b.z = p1[6]; v1b.w = p1[7];
  *(uint4*)d0 = v0a; *(uint4*)(d0 + 8) = v0b;
  *(uint4*)d1 = v1a; *(uint4*)(d1 + 8) = v1b;
}

// ---------- encoder split-K MFMA: block 64co x 128px, 4 waves of 64x32 ----------
// grid (pxT 64, coT 4, kz 2). Each kz writes its OWN slab (plain stores,
// full coverage -> no memset, no atomics).
template<int KIND>  // 0: conv2 (128 chunks), 1: 3x3 (72 chunks)
__global__ __launch_bounds__(256) void k_enc_mfma_split(
    const ushort_t* __restrict__ x0, const ushort_t* __restrict__ x1,
    const ushort_t* __restrict__ wp, float* __restrict__ slab0,
    float* __restrict__ slab1)
{
  __shared__ ushort_t sA[128 * 40];  // [pl(2)*64+row][k32 @pitch40]
  __shared__ ushort_t sB[256 * 40];  // [pl(2)*128+row][k32 @pitch40]
  const int tid = threadIdx.x, lane = tid & 63, wv = tid >> 6;
  const int l15 = lane & 15, q = lane >> 4;
  const int pxT = blockIdx.x, coT = blockIdx.y;
  constexpr int NCH = (KIND == 0) ? 128 : 72;
  const int CH0 = blockIdx.z * (NCH / 2), CH1 = CH0 + NCH / 2;
  float* slab = blockIdx.z ? slab1 : slab0;
  f32x4 acc[4][2];
#pragma unroll
  for (int m = 0; m < 4; ++m)
#pragma unroll
    for (int n = 0; n < 2; ++n) acc[m][n] = (f32x4){0.f, 0.f, 0.f, 0.f};

  // B-row geometry: thread owns row = tid&127, plane = tid>>7
  const int brow = tid & 127;
  const ushort_t* xb = (tid >> 7) ? x1 : x0;
  const int bpx = pxT * 128 + brow;
  const int bimg = bpx >> 10, bp = bpx & 1023, bu = bp >> 5, bvc = bp & 31;
  int ptap = -1; size_t rowb = 0; bool bval = false;

  for (int chunk = CH0; chunk < CH1; ++chunk) {
    const int tap = chunk >> 3, cg = chunk & 7;
    if (tap != ptap) {
      ptap = tap;
      int ky, kx, iy, ix;
      if (KIND == 0) {
        ky = tap >> 2; kx = tap & 3;
        iy = 2 * bu - 1 + ky; ix = 2 * bvc - 1 + kx;
        bval = ((unsigned)iy < 64u) && ((unsigned)ix < 64u);
        rowb = ((size_t)(bimg * 4096 + iy * 64 + ix)) << 8;
      } else {
        ky = tap / 3; kx = tap - ky * 3;
        iy = bu - 1 + ky; ix = bvc - 1 + kx;
        bval = ((unsigned)iy < 32u) && ((unsigned)ix < 32u);
        rowb = ((size_t)(bimg * 1024 + iy * 32 + ix)) << 8;
      }
    }
    // global loads before barrier (overlap with previous MFMA tail)
    uint4 bg[4], ag[2];
    const int koff = cg * 32;
#pragma unroll
    for (int i = 0; i < 4; ++i) {
      if (bval) bg[i] = *(const uint4*)(xb + rowb + koff + i * 8);
      else { bg[i].x = 0; bg[i].y = 0; bg[i].z = 0; bg[i].w = 0; }
    }
    const ushort_t* ap = wp + ((size_t)(chunk * 4 + coT) << 12);  // [pl][64][32] = 4096 elems
    ag[0] = *(const uint4*)(ap + tid * 8);            // coalesced
    ag[1] = *(const uint4*)(ap + (tid + 256) * 8);
    __syncthreads();
#pragma unroll
    for (int i = 0; i < 2; ++i) {
      int idx = tid + 256 * i;                        // linear elem idx/8
      *(uint4*)(&sA[(idx >> 2) * 40 + (idx & 3) * 8]) = ag[i];   // ~3-way, writes only
    }
#pragma unroll
    for (int i = 0; i < 4; ++i)
      *(uint4*)(&sB[tid * 40 + i * 8]) = bg[i];       // rows: 2-way free
    __syncthreads();
    short8 af[4][2], bf[2][2];
#pragma unroll
    for (int m = 0; m < 4; ++m)
#pragma unroll
      for (int pl = 0; pl < 2; ++pl)
        af[m][pl] = *(const short8*)(sA + (pl * 64 + m * 16 + l15) * 40 + q * 8);
#pragma unroll
    for (int n = 0; n < 2; ++n)
#pragma unroll
      for (int pl = 0; pl < 2; ++pl)
        bf[n][pl] = *(const short8*)(sB + (pl * 128 + wv * 32 + n * 16 + l15) * 40 + q * 8);
#pragma unroll
    for (int m = 0; m < 4; ++m)
#pragma unroll
      for (int n = 0; n < 2; ++n) {
        acc[m][n] = __builtin_amdgcn_mfma_f32_16x16x32_bf16(af[m][0], bf[n][0], acc[m][n], 0, 0, 0);
        acc[m][n] = __builtin_amdgcn_mfma_f32_16x16x32_bf16(af[m][0], bf[n][1], acc[m][n], 0, 0, 0);
        acc[m][n] = __builtin_amdgcn_mfma_f32_16x16x32_bf16(af[m][1], bf[n][0], acc[m][n], 0, 0, 0);
      }
  }
  // plain stores to this kz's slab (each element written exactly once)
#pragma unroll
  for (int m = 0; m < 4; ++m) {
#pragma unroll
    for (int n = 0; n < 2; ++n) {
#pragma unroll
      for (int r = 0; r < 4; ++r) {
        const int co_l = m * 16 + q * 4 + r;        // [0,64)
        const int px_l = wv * 32 + n * 16 + l15;    // [0,128)
        const int px = pxT * 128 + px_l;
        const int img = px >> 10, pp = px & 1023;
        const size_t ha = ((size_t)(img * 256 + coT * 64 + co_l)) * 1024 + pp;
        slab[ha] = acc[m][n][r];
      }
    }
  }
}

// ---------- conv2 epilogue 1: h32 = relu(slabA + slabB + bias), elementwise ----
// slabB occupies the h32 region itself (same index) -> in-place safe.
__global__ __launch_bounds__(256) void k_epi_sum_relu(
    const float* __restrict__ slabA, float* __restrict__ slabB_h32,
    const float* __restrict__ bias)
{
  int i = blockIdx.x * 256 + threadIdx.x;  // 2,097,152
  int co = (i >> 10) & 255;
  float v = slabA[i] + slabB_h32[i] + bias[co];
  slabB_h32[i] = fmaxf(v, 0.f);
}

// ---------- conv2 epilogue 2: split-bf16 planes from h32 ----------
__global__ __launch_bounds__(256) void k_split_h(
    const float* __restrict__ h32, ushort_t* __restrict__ s0, ushort_t* __restrict__ s1)
{
  const int px = blockIdx.x * 256 + threadIdx.x;  // 8192
  const int co0 = blockIdx.y * 16;
  const int img = px >> 10, pp = px & 1023;
  uint p0[8], p1[8];
#pragma unroll
  for (int i = 0; i < 8; ++i) {
    size_t ha = ((size_t)(img * 256 + co0 + 2 * i)) * 1024 + pp;
    float sa = h32[ha], sb = h32[ha + 1024];   // already relu'd
    ushort_t a0 = f2bf(sa), b0 = f2bf(sb);
    p0[i] = (uint)a0 | ((uint)b0 << 16);
    p1[i] = (uint)f2bf(sa - bf2f(a0)) | ((uint)f2bf(sb - bf2f(b0)) << 16);
  }
  ushort_t* d0 = s0 + (size_t)px * 256 + co0;
  ushort_t* d1 = s1 + (size_t)px * 256 + co0;
  uint4 v0a; v0a.x = p0[0]; v0a.y = p0[1]; v0a.z = p0[2]; v0a.w = p0[3];
  uint4 v0b; v0b.x = p0[4]; v0b.y = p0[5]; v0b.z = p0[6]; v0b.w = p0[7];
  uint4 v1a; v1a.x = p1[0]; v1a.y = p1[1]; v1a.z = p1[2]; v1a.w = p1[3];
  uint4 v1b; v1b.x = p1[4]; v1b.y = p1[5]; v1b.z = p1[6]; v1b.w = p1[7];
  *(uint4*)d0 = v0a; *(uint4*)(d0 + 8) = v0b;
  *(uint4*)d1 = v1a; *(uint4*)(d1 + 8) = v1b;
}

// ---------- 3x3 epilogue: spB = split(relu(slabA + slabB + bias)) ----------
__global__ __launch_bounds__(256) void k_epi3(
    const float* __restrict__ slabA, const float* __restrict__ slabB,
    const float* __restrict__ bias,
    ushort_t* __restrict__ s0, ushort_t* __restrict__ s1)
{
  const int px = blockIdx.x * 256 + threadIdx.x;  // 8192
  const int co0 = blockIdx.y * 16;
  const int img = px >> 10, pp = px & 1023;
  uint p0[8], p1[8];
#pragma unroll
  for (int i = 0; i < 8; ++i) {
    size_t ha = ((size_t)(img * 256 + co0 + 2 * i)) * 1024 + pp;
    size_t hb = ha + 1024;
    float sa = fmaxf(slabA[ha] + slabB[ha] + bias[co0 + 2 * i], 0.f);
    float sb = fmaxf(slabA[hb] + slabB[hb] + bias[co0 + 2 * i + 1], 0.f);
    ushort_t a0 = f2bf(sa), b0 = f2bf(sb);
    p0[i] = (uint)a0 | ((uint)b0 << 16);
    p1[i] = (uint)f2bf(sa - bf2f(a0)) | ((uint)f2bf(sb - bf2f(b0)) << 16);
  }
  ushort_t* d0 = s0 + (size_t)px * 256 + co0;
  ushort_t* d1 = s1 + (size_t)px * 256 + co0;
  uint4 v0a; v0a.x = p0[0]; v0a.y = p0[1]; v0a.z = p0[2]; v0a.w = p0[3];
  uint4 v0b; v0b.x = p0[4]; v0b.y = p0[5]; v0b.z = p0[6]; v0b.w = p0[7];
  uint4 v1a; v1a.x = p1[0]; v1a.y = p1[1]; v1a.z = p1[2]; v1a.w = p1[3];
  uint4 v1b; v1b.x = p1[4]; v1b.y = p1[5]; v1b.z = p1[6]; v1b.w = p1[7];
  *(uint4*)d0 = v0a; *(uint4*)(d0 + 8) = v0b;
  *(uint4*)d1 = v1a; *(uint4*)(d1 + 8) = v1b;
}

// ---------- encoder 1x1 MFMA (h += conv(spB); optional split-out) ----------
// Block 64co x 128px, 4 waves 64x32; 8 chunks; pitch-40 LDS.
template<bool WS>
__global__ __launch_bounds__(256) void k_enc_1x1(
    const ushort_t* __restrict__ x0, const ushort_t* __restrict__ x1,
    const ushort_t* __restrict__ wp, const float* __restrict__ bias,
    float* __restrict__ h32, ushort_t* __restrict__ sp0, ushort_t* __restrict__ sp1)
{
  __shared__ ushort_t smem[18432];   // sA 128*40 | sB 256*40 ; epilogue: 2x128x72
  ushort_t* sA = smem;               // [pl*64+row][k32 @40]
  ushort_t* sB = smem + 5120;        // [pl*128+row][k32 @40]
  const int tid = threadIdx.x, lane = tid & 63, wv = tid >> 6;
  const int l15 = lane & 15, q = lane >> 4;
  const int pxT = blockIdx.x, coT = blockIdx.y;
  f32x4 acc[4][2];
#pragma unroll
  for (int m = 0; m < 4; ++m)
#pragma unroll
    for (int n = 0; n < 2; ++n) acc[m][n] = (f32x4){0.f, 0.f, 0.f, 0.f};

  const int brow = tid & 127;
  const ushort_t* xb = (tid >> 7) ? x1 : x0;
  const size_t rowb = ((size_t)(pxT * 128 + brow)) << 8;

  for (int chunk = 0; chunk < 8; ++chunk) {
    uint4 bg[4], ag[2];
    const int koff = chunk * 32;
#pragma unroll
    for (int i = 0; i < 4; ++i) bg[i] = *(const uint4*)(xb + rowb + koff + i * 8);
    const ushort_t* ap = wp + ((size_t)(chunk * 4 + coT) << 12);  // [pl][64][32] = 4096
#pragma unroll
    for (int i = 0; i < 2; ++i) {
      int idx = tid + 256 * i;                 // 0..511
      ag[i] = *(const uint4*)(ap + (idx & 127) * 32 + (idx >> 7) * 8);
    }
    __syncthreads();
#pragma unroll
    for (int i = 0; i < 2; ++i) {
      int idx = tid + 256 * i;
      *(uint4*)(&sA[(idx & 127) * 40 + (idx >> 7) * 8]) = ag[i];
    }
#pragma unroll
    for (int i = 0; i < 4; ++i)
      *(uint4*)(&sB[tid * 40 + i * 8]) = bg[i];
    __syncthreads();
    short8 af[4][2], bf[2][2];
#pragma unroll
    for (int m = 0; m < 4; ++m)
#pragma unroll
      for (int pl = 0; pl < 2; ++pl)
        af[m][pl] = *(const short8*)(sA + (pl * 64 + m * 16 + l15) * 40 + q * 8);
#pragma unroll
    for (int n = 0; n < 2; ++n)
#pragma unroll
      for (int pl = 0; pl < 2; ++pl)
        bf[n][pl] = *(const short8*)(sB + (pl * 128 + wv * 32 + n * 16 + l15) * 40 + q * 8);
#pragma unroll
    for (int m = 0; m < 4; ++m)
#pragma unroll
      for (int n = 0; n < 2; ++n) {
        acc[m][n] = __builtin_amdgcn_mfma_f32_16x16x32_bf16(af[m][0], bf[n][0], acc[m][n], 0, 0, 0);
        acc[m][n] = __builtin_amdgcn_mfma_f32_16x16x32_bf16(af[m][0], bf[n][1], acc[m][n], 0, 0, 0);
        acc[m][n] = __builtin_amdgcn_mfma_f32_16x16x32_bf16(af[m][1], bf[n][0], acc[m][n], 0, 0, 0);
      }
  }
  __syncthreads();
  // epilogue: h += v (+bias); optionally split(relu(h)) via smem
#pragma unroll
  for (int m = 0; m < 4; ++m) {
#pragma unroll
    for (int n = 0; n < 2; ++n) {
#pragma unroll
      for (int r = 0; r < 4; ++r) {
        const int co_l = m * 16 + q * 4 + r;        // [0,64)
        const int px_l = wv * 32 + n * 16 + l15;    // [0,128)
        float v = acc[m][n][r] + bias[coT * 64 + co_l];
        const int px = pxT * 128 + px_l;
        const int img = px >> 10, pp = px & 1023;
        const size_t ha = ((size_t)(img * 256 + coT * 64 + co_l)) * 1024 + pp;
        v += h32[ha];
        h32[ha] = v;
        if (WS) {
          float sv = fmaxf(v, 0.f);
          ushort_t b0 = f2bf(sv);
          smem[px_l * 72 + co_l] = b0;
          smem[9216 + px_l * 72 + co_l] = f2bf(sv - bf2f(b0));
        }
      }
    }
  }
  if (WS) {
    __syncthreads();
#pragma unroll
    for (int i = 0; i < 8; ++i) {
      int idx = tid + 256 * i;
      int pl = idx >> 10, w2 = idx & 1023, pxl = w2 >> 3, g = w2 & 7;
      uint4 vv = *(const uint4*)(smem + pl * 9216 + pxl * 72 + g * 8);
      ushort_t* dst = (pl ? sp1 : sp0) + ((size_t)(pxT * 128 + pxl)) * 256 + coT * 64 + g * 8;
      *(uint4*)dst = vv;
    }
  }
}

// ---------- 1x1 conv fp32 (to_z only) ----------
__global__ __launch_bounds__(256) void k_conv1x1(
    const float* __restrict__ in, float* __restrict__ out,
    const float* __restrict__ wT, const float* __restrict__ bias,
    int CI, int CO, int P)
{
  const int p = blockIdx.x * 256 + threadIdx.x;
  const int cob = blockIdx.y * 16;
  const int n = blockIdx.z;
  const float* inN = in + (size_t)n * CI * P + p;
  float acc[16];
#pragma unroll
  for (int i = 0; i < 16; ++i) acc[i] = bias[cob + i];
  const float* wr = wT + cob;
#pragma unroll 4
  for (int ci = 0; ci < CI; ++ci) {
    float iv = inN[(size_t)ci * P];
    const float* w = wr + (size_t)ci * CO;  // uniform
#pragma unroll
    for (int i = 0; i < 16; ++i) acc[i] = fmaf(iv, w[i], acc[i]);
  }
  float* outN = out + (size_t)n * CO * P + p;
#pragma unroll
  for (int i = 0; i < 16; ++i) outN[(size_t)(cob + i) * P] = acc[i];
}

// ---------- VQ partial: 16 chunks of 32 codes ----------
__global__ __launch_bounds__(256) void k_vq_part(
    const float* __restrict__ z_e, const float* __restrict__ cb,
    const float* __restrict__ cnorm, float* __restrict__ pbest, int* __restrict__ pbid)
{
  int g = blockIdx.x * 256 + threadIdx.x;  // 8192 points
  int chunk = blockIdx.y;                  // 16 chunks
  int img = g >> 10, p = g & 1023;
  const float* zp = z_e + (size_t)img * 64 * 1024 + p;
  float z[64];
#pragma unroll
  for (int c = 0; c < 64; ++c) z[c] = zp[(size_t)c * 1024];
  float best = 3.4e38f; int bid = chunk << 5;
  const int j0 = chunk << 5;
  for (int j = j0; j < j0 + 32; ++j) {
    const float* cj = cb + j * 64;  // uniform -> scalar loads
    float m = 0.f;
#pragma unroll
    for (int c = 0; c < 64; ++c) m = fmaf(z[c], cj[c], m);
    float d = fmaf(-2.f, m, cnorm[j]);
    if (d < best) { best = d; bid = j; }  // strict <: first-min within chunk
  }
  pbest[chunk * 8192 + g] = best;
  pbid[chunk * 8192 + g] = bid;
}

// ---------- VQ reduce (ascending chunks -> np.argmin) + e_k gather ----------
__global__ __launch_bounds__(256) void k_vq_reduce(
    const float* __restrict__ pbest, const int* __restrict__ pbid,
    const float* __restrict__ cb, float* __restrict__ ids_f, float* __restrict__ ek)
{
  int g = blockIdx.x * 256 + threadIdx.x;  // 8192
  float best = 3.4e38f; int bid = 0;
#pragma unroll
  for (int ch = 0; ch < 16; ++ch) {
    float d = pbest[ch * 8192 + g];
    int b = pbid[ch * 8192 + g];
    if (d < best) { best = d; bid = b; }
  }
  ids_f[g] = (float)bid;
  int img = g >> 10, p = g & 1023;
  const float* cbid = cb + bid * 64;
  float* ekp = ek + (size_t)img * 64 * 1024 + p;
#pragma unroll
  for (int c = 0; c < 64; ++c) ekp[(size_t)c * 1024] = cbid[c];
}

// ---------- from_z 1x1 (64->256) + relu -> NHWC bf16 ----------
__global__ __launch_bounds__(256) void k_from_z(
    const float* __restrict__ ek, ushort_t* __restrict__ nhwc,
    const float* __restrict__ wT, const float* __restrict__ bias)
{
  const int p = blockIdx.x * 256 + threadIdx.x;  // 0..1023
  const int co0 = blockIdx.y * 16;
  const int n = blockIdx.z;
  const float* inN = ek + (size_t)n * 64 * 1024 + p;
  float acc[16];
#pragma unroll
  for (int i = 0; i < 16; ++i) acc[i] = bias[co0 + i];
#pragma unroll 4
  for (int ci = 0; ci < 64; ++ci) {
    float iv = inN[(size_t)ci * 1024];
    const float* w = wT + (size_t)ci * 256 + co0;  // uniform
#pragma unroll
    for (int i = 0; i < 16; ++i) acc[i] = fmaf(iv, w[i], acc[i]);
  }
  uint pk[8];
#pragma unroll
  for (int i = 0; i < 8; ++i) {
    ushort_t lo = f2bf(fmaxf(acc[2 * i], 0.f));
    ushort_t hi = f2bf(fmaxf(acc[2 * i + 1], 0.f));
    pk[i] = (uint)lo | ((uint)hi << 16);
  }
  ushort_t* op = nhwc + (((size_t)n * 1024 + p) * 256 + co0);
  uint4 v0; v0.x = pk[0]; v0.y = pk[1]; v0.z = pk[2]; v0.w = pk[3];
  uint4 v1; v1.x = pk[4]; v1.y = pk[5]; v1.z = pk[6]; v1.w = pk[7];
  *(uint4*)(op) = v0;
  *(uint4*)(op + 8) = v1;
}

// ---------- t1 convtranspose 4x4 s2 p1, 256->256, bf16 MFMA -> bf16 NHWC ----
__global__ __launch_bounds__(256) void k_mfma_t1(
    const ushort_t* __restrict__ nhwc, const ushort_t* __restrict__ wb,
    const float* __restrict__ bias, ushort_t* __restrict__ t1o)
{
  __shared__ ushort_t sA[128 * 40];
  __shared__ ushort_t sB[128 * 40];
  const int tid = threadIdx.x;
  const int lane = tid & 63;
  const int wv = tid >> 6;
  const int wm = wv & 1, wn = wv >> 1;
  const int l15 = lane & 15, q = lane >> 4;
  const int pxT = blockIdx.x, coT = blockIdx.y, par = blockIdx.z;
  const int ry = par & 1, rx = (par >> 1) & 1;
  const int pxbase = pxT * 128;
  const int img = pxbase >> 10;
  f32x4 acc[4][4];
#pragma unroll
  for (int i = 0; i < 4; ++i)
#pragma unroll
    for (int j = 0; j < 4; ++j) acc[i][j] = (f32x4){0.f, 0.f, 0.f, 0.f};

  for (int c = 0; c < 32; ++c) {
    const int tap = c >> 3, c8 = c & 7;
    const int a = tap >> 1, b = tap & 1;
    const ushort_t* Abase = wb + ((size_t)((par * 4 + tap) * 8 + c8) << 13);
    uint4 av[2], bvv[2];
#pragma unroll
    for (int r = 0; r < 2; ++r) {
      int idx = tid + 256 * r;             // 0..511
      int row = idx & 127, kg = idx >> 7;  // kg 0..3
      av[r] = *(const uint4*)(Abase + ((coT * 128 + row) * 32 + kg * 8));
      int px = pxbase + row;
      int u = (px >> 5) & 31, vv = px & 31;
      int iy = u + ry - a, ix = vv + rx - b;
      if ((unsigned)iy < 32u && (unsigned)ix < 32u)
        bvv[r] = *(const uint4*)(nhwc + ((size_t)(img * 1024 + iy * 32 + ix) * 256 + c8 * 32 + kg * 8));
      else { bvv[r].x = 0u; bvv[r].y = 0u; bvv[r].z = 0u; bvv[r].w = 0u; }
    }
    __syncthreads();
#pragma unroll
    for (int r = 0; r < 2; ++r) {
      int idx = tid + 256 * r;
      int row = idx & 127, kg = idx >> 7;
      *(uint4*)(&sA[row * 40 + kg * 8]) = av[r];
      *(uint4*)(&sB[row * 40 + kg * 8]) = bvv[r];
    }
    __syncthreads();
    short8 af[4], bfr[4];
#pragma unroll
    for (int i = 0; i < 4; ++i)
      af[i] = *(const short8*)(sA + (wm * 64 + i * 16 + l15) * 40 + q * 8);
#pragma unroll
    for (int j = 0; j < 4; ++j)
      bfr[j] = *(const short8*)(sB + (wn * 64 + j * 16 + l15) * 40 + q * 8);
#pragma unroll
    for (int i = 0; i < 4; ++i)
#pragma unroll
      for (int j = 0; j < 4; ++j)
        acc[i][j] = __builtin_amdgcn_mfma_f32_16x16x32_bf16(af[i], bfr[j], acc[i][j], 0, 0, 0);
  }
#pragma unroll
  for (int i = 0; i < 4; ++i) {
    int co = coT * 128 + wm * 64 + i * 16 + q * 4;
#pragma unroll
    for (int j = 0; j < 4; ++j) {
      int px = pxbase + wn * 64 + j * 16 + l15;
      int u = (px >> 5) & 31, vv = px & 31;
      int oy = 2 * u + ry, ox = 2 * vv + rx;
      ushort_t e0 = f2bf(fmaxf(acc[i][j][0] + bias[co + 0], 0.f));
      ushort_t e1 = f2bf(fmaxf(acc[i][j][1] + bias[co + 1], 0.f));
      ushort_t e2 = f2bf(fmaxf(acc[i][j][2] + bias[co + 2], 0.f));
      ushort_t e3 = f2bf(fmaxf(acc[i][j][3] + bias[co + 3], 0.f));
      uint2 pk; pk.x = (uint)e0 | ((uint)e1 << 16); pk.y = (uint)e2 | ((uint)e3 << 16);
      *(uint2*)(t1o + ((size_t)(img * 4096 + oy * 64 + ox) * 256 + co)) = pk;
    }
  }
}

// ---------- t2 convtranspose 4x4 s2 p1, 256->3, bf16 MFMA, sigmoid ----------
__global__ __launch_bounds__(256) void k_mfma_t2(
    const ushort_t* __restrict__ t1o, const ushort_t* __restrict__ wb,
    const float* __restrict__ bias, float* __restrict__ out)
{
  __shared__ ushort_t sA2[256 * 40];
  __shared__ ushort_t sB2[16 * 40];
  const int tid = threadIdx.x, lane = tid & 63, wv = tid >> 6;
  const int l15 = lane & 15, q = lane >> 4;
  const int pxb = blockIdx.x * 256;
  const int par = blockIdx.y;
  const int ry = par & 1, rx = (par >> 1) & 1;
  f32x4 acc[4];
#pragma unroll
  for (int m = 0; m < 4; ++m) acc[m] = (f32x4){0.f, 0.f, 0.f, 0.f};
  const int px = pxb + tid;
  const int pimg = px >> 12, pp = px & 4095, pu = pp >> 6, pv = pp & 63;
  size_t rb = 0; bool rv = false;
  for (int chunk = 0; chunk < 32; ++chunk) {
    const int tap = chunk >> 3, cg = chunk & 7;
    if ((chunk & 7) == 0) {
      const int a = tap >> 1, b = tap & 1;
      int iy = pu + ry - a, ix = pv + rx - b;
      rv = ((unsigned)iy < 64u) && ((unsigned)ix < 64u);
      rb = ((size_t)(pimg * 4096 + iy * 64 + ix)) << 8;
    }
    uint4 av[4];
#pragma unroll
    for (int kg = 0; kg < 4; ++kg) {
      if (rv) av[kg] = *(const uint4*)(t1o + rb + cg * 32 + kg * 8);
      else { av[kg].x = 0; av[kg].y = 0; av[kg].z = 0; av[kg].w = 0; }
    }
    uint4 bv;
    if (tid < 64) {
      int co = tid & 15, kgb = tid >> 4;
      bv = *(const uint4*)(wb + ((size_t)(par * 32 + chunk) * 16 + co) * 32 + kgb * 8);
    }
    __syncthreads();
#pragma unroll
    for (int kg = 0; kg < 4; ++kg)
      *(uint4*)(&sA2[tid * 40 + kg * 8]) = av[kg];
    if (tid < 64) {
      int co = tid & 15, kgb = tid >> 4;
      *(uint4*)(&sB2[co * 40 + kgb * 8]) = bv;
    }
    __syncthreads();
    short8 bf = *(const short8*)(sB2 + l15 * 40 + q * 8);
#pragma unroll
    for (int m = 0; m < 4; ++m) {
      short8 af = *(const short8*)(sA2 + (wv * 64 + m * 16 + l15) * 40 + q * 8);
      acc[m] = __builtin_amdgcn_mfma_f32_16x16x32_bf16(af, bf, acc[m], 0, 0, 0);
    }
    __syncthreads();
  }
  const int co = l15;
  if (co < 3) {
    float bco = bias[co];
#pragma unroll
    for (int m = 0; m < 4; ++m) {
#pragma unroll
      for (int r = 0; r < 4; ++r) {
        int opx = pxb + wv * 64 + m * 16 + q * 4 + r;
        int img = opx >> 12, p = opx & 4095, u = p >> 6, v = p & 63;
        size_t addr = ((size_t)(img * 3 + co)) * 16384 + (2 * u + ry) * 128 + (2 * v + rx);
        out[addr] = 1.f / (1.f + expf(-(acc[m][r] + bco)));
      }
    }
  }
}

// ---------------------------------------------------------------------------
extern "C" void kernel_launch(void* const* d_in, const int* in_sizes, int n_in,
                              void* d_out, int out_size, void* d_ws, size_t ws_size,
                              hipStream_t stream) {
  (void)in_sizes; (void)n_in; (void)out_size; (void)ws_size;
  const float* x      = (const float*)d_in[0];
  const float* c1_w   = (const float*)d_in[1];
  const float* c1_b   = (const float*)d_in[2];
  const float* c2_w   = (const float*)d_in[3];
  const float* c2_b   = (const float*)d_in[4];
  const float* r0_w3  = (const float*)d_in[5];
  const float* r0_b3  = (const float*)d_in[6];
  const float* r0_w1  = (const float*)d_in[7];
  const float* r0_b1  = (const float*)d_in[8];
  const float* r1_w3  = (const float*)d_in[9];
  const float* r1_b3  = (const float*)d_in[10];
  const float* r1_w1  = (const float*)d_in[11];
  const float* r1_b1  = (const float*)d_in[12];
  const float* to_z_w = (const float*)d_in[13];
  const float* to_z_b = (const float*)d_in[14];
  const float* cb     = (const float*)d_in[15];
  const float* from_z_w = (const float*)d_in[16];
  const float* from_z_b = (const float*)d_in[17];
  const float* t1_w   = (const float*)d_in[18];
  const float* t1_b   = (const float*)d_in[19];
  const float* t2_w   = (const float*)d_in[20];
  const float* t2_b   = (const float*)d_in[21];

  float* wsf = (float*)d_ws;
  // era-overlapped regions (float offsets):
  ushort_t* xs1p0 = (ushort_t*)(wsf + 0);        // conv1-era [0, 4.19M)
  ushort_t* xs1p1 = (ushort_t*)(wsf + 4194304);  // conv1-era [4.19M, 8.39M)
  ushort_t* spB0  = (ushort_t*)(wsf + 0);        // res-era   [0, 1.05M)
  ushort_t* spB1  = (ushort_t*)(wsf + 1048576);  // res-era   [1.05M, 2.1M)
  float*    pbest = wsf + 0;                     // vq-era
  int*      pbid  = (int*)(wsf + 131072);        // vq-era
  float*    slabC = wsf + 2097152;               // 3x3-era [2.1M, 4.19M)
  float*    slabD = wsf + 4194304;               // 3x3-era [4.19M, 6.29M)
  ushort_t* t1out = (ushort_t*)(wsf + 2097152);  // dec-era [2.1M, 6.29M)
  ushort_t* decn  = (ushort_t*)(wsf + 6291456);  // dec-era [6.29M, 7.34M)
  float*    h32   = wsf + 8388608;               // [8.39M, 10.49M); conv2 slabB (in-place)
  float*    slabA = wsf + 10485760;              // conv2-era; becomes spA region after epi1
  ushort_t* spA0  = (ushort_t*)(wsf + 10485760);
  ushort_t* spA1  = (ushort_t*)(wsf + 11534336);
  ushort_t* wp_c2   = (ushort_t*)(wsf + 12582912);
  ushort_t* wp_r0w3 = (ushort_t*)(wsf + 13631488);
  ushort_t* wp_r1w3 = (ushort_t*)(wsf + 14221312);
  ushort_t* wp_r0w1 = (ushort_t*)(wsf + 14811136);
  ushort_t* wp_r1w1 = (ushort_t*)(wsf + 14876672);
  float*    wt_c1   = wsf + 14942208;
  float*    wt_toz  = wsf + 14954496;
  float*    wt_fromz= wsf + 14970880;
  ushort_t* t1wb    = (ushort_t*)(wsf + 14987264);
  ushort_t* w2pk    = (ushort_t*)(wsf + 15511552);
  float*    cnorm   = wsf + 15544320;

  float* out_img = (float*)d_out;        // 393216
  float* z_e_out = out_img + 393216;     // 524288
  float* e_k_out = z_e_out + 524288;     // 524288
  float* ids_out = e_k_out + 524288;     // 8192 (stored as float)

  // ---- weight prep ----
  k_transpose_w<<<48, 256, 0, stream>>>(c1_w, wt_c1, 256, 48);
  k_transpose_w<<<64, 256, 0, stream>>>(to_z_w, wt_toz, 64, 256);
  k_transpose_w<<<64, 256, 0, stream>>>(from_z_w, wt_fromz, 256, 64);
  k_prep_enc<0><<<8192, 256, 0, stream>>>(c2_w,  wp_c2,   128 << 14);
  k_prep_enc<1><<<4608, 256, 0, stream>>>(r0_w3, wp_r0w3, 72 << 14);
  k_prep_enc<1><<<4608, 256, 0, stream>>>(r1_w3, wp_r1w3, 72 << 14);
  k_prep_enc<2><<<512,  256, 0, stream>>>(r0_w1, wp_r0w1, 8 << 14);
  k_prep_enc<2><<<512,  256, 0, stream>>>(r1_w1, wp_r1w1, 8 << 14);
  k_prep_t1w<<<4096, 256, 0, stream>>>(t1_w, t1wb);
  k_prep_t2w<<<256, 256, 0, stream>>>(t2_w, w2pk);
  k_prep_cb<<<2, 256, 0, stream>>>(cb, cnorm);

  // ---- encoder ----
  k_conv1_split<<<dim3(64, 4, 8), 256, 0, stream>>>(x, xs1p0, xs1p1, wt_c1, c1_b);
  // conv2: split-K=2 -> slabA + slabB(=h32 region); epi1 sums elementwise; epi2 splits
  k_enc_mfma_split<0><<<dim3(64, 4, 2), 256, 0, stream>>>(xs1p0, xs1p1, wp_c2, slabA, h32);
  k_epi_sum_relu<<<8192, 256, 0, stream>>>(slabA, h32, c2_b);
  k_split_h<<<dim3(32, 16), 256, 0, stream>>>(h32, spA0, spA1);
  // r0 w3: split-K=2 -> slabC/D (conv1-output region, dead); epi3 -> spB
  k_enc_mfma_split<1><<<dim3(64, 4, 2), 256, 0, stream>>>(spA0, spA1, wp_r0w3, slabC, slabD);
  k_epi3<<<dim3(32, 16), 256, 0, stream>>>(slabC, slabD, r0_b3, spB0, spB1);
  // r0 w1: h += conv; write h32 + split(relu(h)) -> spA
  k_enc_1x1<true><<<dim3(64, 4), 256, 0, stream>>>(spB0, spB1, wp_r0w1, r0_b1, h32, spA0, spA1);
  // r1 w3
  k_enc_mfma_split<1><<<dim3(64, 4, 2), 256, 0, stream>>>(spA0, spA1, wp_r1w3, slabC, slabD);
  k_epi3<<<dim3(32, 16), 256, 0, stream>>>(slabC, slabD, r1_b3, spB0, spB1);
  // r1 w1: h += conv; write h32 only
  k_enc_1x1<false><<<dim3(64, 4), 256, 0, stream>>>(spB0, spB1, wp_r1w1, r1_b1, h32, nullptr, nullptr);
  // to_z (fp32)
  k_conv1x1<<<dim3(4, 4, 8), 256, 0, stream>>>(h32, z_e_out, wt_toz, to_z_b, 256, 64, 1024);

  // ---- VQ (chunk-parallel; bit-identical argmin) ----
  k_vq_part<<<dim3(32, 16), 256, 0, stream>>>(z_e_out, cb, cnorm, pbest, pbid);
  k_vq_reduce<<<32, 256, 0, stream>>>(pbest, pbid, cb, ids_out, e_k_out);

  // ---- decoder (bf16) ----
  k_from_z<<<dim3(4, 16, 8), 256, 0, stream>>>(e_k_out, decn, wt_fromz, from_z_b);
  k_mfma_t1<<<dim3(64, 2, 4), 256, 0, stream>>>(decn, t1wb, t1_b, t1out);
  k_mfma_t2<<<dim3(128, 4), 256, 0, stream>>>(t1out, w2pk, t2_b, out_img);
}

// Round 7
// 638.063 us; speedup vs baseline: 1.1393x; 1.1393x over previous
//
#include <hip/hip_runtime.h>
#include <math.h>

// ---------------------------------------------------------------------------
// VQ-VAE forward.
// Encoder: 256-ch convs as implicit-GEMM MFMA with 2-term bf16 split inputs
// (3 passes: w1x1 + w1x2 + w2x1). Big convs: round-4 loop geometry VERBATIM
// (64co x 128px blocks, pitch-32 LDS, paired B-row loads -- 82us measured;
// round-6's pitch-40 restructure doubled it), with two deltas:
//  (1) split-K=2 into per-kz slabs (plain stores; round-5 showed cross-XCD
//      atomicAdd writes 10x traffic), fixed-order reduce in epilogue kernels;
//  (2) double-buffered LDS K-loop: ONE barrier/chunk, prefetch chunk c+1
//      globals into regs during chunk c MFMAs (attacks the ~40% barrier-drain
//      stall at 2 blocks/CU).
// VQ: chunk-parallel partial argmin + reduce; bit-identical to serial.
// ---------------------------------------------------------------------------

typedef unsigned int uint;
typedef unsigned short ushort_t;
using short8 = __attribute__((ext_vector_type(8))) short;
using f32x4  = __attribute__((ext_vector_type(4))) float;

static __device__ __forceinline__ ushort_t f2bf(float f) {
  uint u = __float_as_uint(f);
  return (ushort_t)((u + 0x7fffu + ((u >> 16) & 1u)) >> 16);  // RNE; finite inputs
}
static __device__ __forceinline__ float bf2f(ushort_t b) {
  return __uint_as_float(((uint)b) << 16);
}

// ---------- weight prep ----------
__global__ void k_transpose_w(const float* __restrict__ w, float* __restrict__ wT, int CO, int CIKK) {
  int idx = blockIdx.x * 256 + threadIdx.x;
  if (idx >= CO * CIKK) return;
  int co = idx % CO, i = idx / CO;
  wT[idx] = w[co * CIKK + i];
}

// encoder MFMA weight pack: w[co][ci(256)][KH][KW] fp32 ->
// wp[chunk][coT(4)][pl(2)][row(64)][k(32)] bf16 split, chunk = tap*8 + cg
template<int KIND>  // 0: 4x4 (16 taps), 1: 3x3 (9 taps), 2: 1x1 (1 tap)
__global__ void k_prep_enc(const float* __restrict__ w, ushort_t* __restrict__ wp, int total) {
  int idx = blockIdx.x * 256 + threadIdx.x;
  if (idx >= total) return;
  int k = idx & 31, row = (idx >> 5) & 63, pl = (idx >> 11) & 1, coT = (idx >> 12) & 3, chunk = idx >> 14;
  int tap = chunk >> 3, cg = chunk & 7;
  int co = coT * 64 + row, ci = cg * 32 + k;
  int ky, kx, KK, KW;
  if (KIND == 0)      { ky = tap >> 2; kx = tap & 3;       KK = 16; KW = 4; }
  else if (KIND == 1) { ky = tap / 3;  kx = tap - ky * 3;  KK = 9;  KW = 3; }
  else                { ky = 0;        kx = 0;             KK = 1;  KW = 1; }
  float v = w[(co * 256 + ci) * KK + ky * KW + kx];
  ushort_t b0 = f2bf(v);
  wp[idx] = pl ? f2bf(v - bf2f(b0)) : b0;
}

// t1_w [ci][co][ky][kx] -> bf16 [par][tap][c8][co][kk32]
__global__ void k_prep_t1w(const float* __restrict__ w, ushort_t* __restrict__ wb) {
  int idx = blockIdx.x * 256 + threadIdx.x;  // 1048576
  int kk  = idx & 31;
  int co  = (idx >> 5) & 255;
  int c8  = (idx >> 13) & 7;
  int tap = (idx >> 16) & 3;
  int par = idx >> 18;
  int ry = par & 1, rx = (par >> 1) & 1;
  int a = tap >> 1, b = tap & 1;
  int ky = ((ry + 1) & 1) + 2 * a;
  int kx = ((rx + 1) & 1) + 2 * b;
  int ci = c8 * 32 + kk;
  wb[idx] = f2bf(w[((ci * 256 + co) << 4) + ky * 4 + kx]);
}

// t2_w [ci(256)][co(3)][4][4] -> bf16 [par(4)][chunk(32)][co16][k32]
__global__ void k_prep_t2w(const float* __restrict__ w, ushort_t* __restrict__ wb) {
  int idx = blockIdx.x * 256 + threadIdx.x;  // 65536
  int k = idx & 31, co = (idx >> 5) & 15, chunk = (idx >> 9) & 31, par = idx >> 14;
  int tap = chunk >> 3, cg = chunk & 7;
  int a = tap >> 1, b = tap & 1;
  int ry = par & 1, rx = (par >> 1) & 1;
  int ky = ((ry + 1) & 1) + 2 * a;
  int kx = ((rx + 1) & 1) + 2 * b;
  int ci = cg * 32 + k;
  float v = (co < 3) ? w[((ci * 3 + co) << 4) + ky * 4 + kx] : 0.f;
  wb[idx] = f2bf(v);
}

// cnorm[j] = sum_c cb[j][c]^2
__global__ void k_prep_cb(const float* __restrict__ cb, float* __restrict__ cnorm) {
  int idx = blockIdx.x * 256 + threadIdx.x;
  if (idx < 512) {
    float s = 0.f;
    for (int c = 0; c < 64; ++c) { float v = cb[idx * 64 + c]; s = fmaf(v, v, s); }
    cnorm[idx] = s;
  }
}

// ---------- conv1: 3->256, 4x4 s2 p1, relu, output split-bf16 NHWC ----------
__global__ __launch_bounds__(256) void k_conv1_split(
    const float* __restrict__ in, ushort_t* __restrict__ o0, ushort_t* __restrict__ o1,
    const float* __restrict__ wT, const float* __restrict__ bias)
{
  __shared__ float s_in[3 * 360];  // parity-split cols, pitch 20 (2-way free)
  const int tid = threadIdx.x;
  const int lane = tid & 63;
  const int wv = __builtin_amdgcn_readfirstlane(tid >> 6);
  const int px = lane & 7, py = lane >> 3;
  const int tx = blockIdx.x & 7, ty = blockIdx.x >> 3;
  const int X = tx * 8, Y = ty * 8;
  const int cob = blockIdx.y * 64 + wv * 16;
  const int n = blockIdx.z;
  float acc[16];
#pragma unroll
  for (int i = 0; i < 16; ++i) acc[i] = bias[cob + i];
  const float* inN = in + (size_t)n * 3 * 16384;
  for (int e = tid; e < 3 * 360; e += 256) {
    int col2 = e % 20; int t = e / 20; int row = t % 18; int ci = t / 18;
    int pr = col2 / 10, hc = col2 % 10, ixl = 2 * hc + pr;
    int iy = 2 * Y - 1 + row, ix = 2 * X - 1 + ixl;
    float v = 0.f;
    if (ixl < 18 && (unsigned)iy < 128u && (unsigned)ix < 128u)
      v = inN[ci * 16384 + iy * 128 + ix];
    s_in[e] = v;
  }
  __syncthreads();
  const float* wc = wT + cob;
#pragma unroll
  for (int c = 0; c < 3; ++c) {
    const float* base = s_in + c * 360 + py * 40 + px;
#pragma unroll
    for (int ky = 0; ky < 4; ++ky) {
#pragma unroll
      for (int kx = 0; kx < 4; ++kx) {
        float iv = base[ky * 20 + (kx & 1) * 10 + (kx >> 1)];
        const float* w = wc + (size_t)(c * 16 + ky * 4 + kx) * 256;  // uniform
#pragma unroll
        for (int i = 0; i < 16; ++i) acc[i] = fmaf(iv, w[i], acc[i]);
      }
    }
  }
  const int pxg = n * 4096 + (Y + py) * 64 + (X + px);
  uint p0[8], p1[8];
#pragma unroll
  for (int i = 0; i < 8; ++i) {
    float va = fmaxf(acc[2 * i], 0.f), vb = fmaxf(acc[2 * i + 1], 0.f);
    ushort_t a0 = f2bf(va), b0 = f2bf(vb);
    ushort_t a1 = f2bf(va - bf2f(a0)), b1 = f2bf(vb - bf2f(b0));
    p0[i] = (uint)a0 | ((uint)b0 << 16);
    p1[i] = (uint)a1 | ((uint)b1 << 16);
  }
  ushort_t* d0 = o0 + (size_t)pxg * 256 + cob;
  ushort_t* d1 = o1 + (size_t)pxg * 256 + cob;
  uint4 v0a; v0a.x = p0[0]; v0a.y = p0[1]; v0a.z = p0[2]; v0a.w = p0[3];
  uint4 v0b; v0b.x = p0[4]; v0b.y = p0[5]; v0b.z = p0[6]; v0b.w = p0[7];
  uint4 v1a; v1a.x = p1[0]; v1a.y = p1[1]; v1a.z = p1[2]; v1a.w = p1[3];
  uint4 v1b; v1b.x = p1[4]; v1b.y = p1[5]; v1b.z = p1[6]; v1b.w = p1[7];
  *(uint4*)d0 = v0a; *(uint4*)(d0 + 8) = v0b;
  *(uint4*)d1 = v1a; *(uint4*)(d1 + 8) = v1b;
}

// ---------- encoder split-K MFMA: round-4 loop + double-buffered LDS ----------
// Block 64co x 128px, 4 waves of 64x32; grid (pxT 64, coT 4, kz 2).
// Each kz writes its own slab (plain stores, full coverage).
template<int KIND>  // 0: conv2 (128 chunks), 1: 3x3 (72 chunks)
__global__ __launch_bounds__(256) void k_enc_mfma_split(
    const ushort_t* __restrict__ x0, const ushort_t* __restrict__ x1,
    const ushort_t* __restrict__ wp, float* __restrict__ slab0,
    float* __restrict__ slab1)
{
  __shared__ ushort_t sA[2 * 4096];  // [buf][pl*2048 + row64*32 + k]  (pitch 32)
  __shared__ ushort_t sB[2 * 8192];  // [buf][pl*4096 + row128*32 + k]
  const int tid = threadIdx.x, lane = tid & 63, wv = tid >> 6;
  const int l15 = lane & 15, q = lane >> 4;
  const int pxT = blockIdx.x, coT = blockIdx.y;
  constexpr int NCH = (KIND == 0) ? 128 : 72;
  const int CH0 = blockIdx.z * (NCH / 2), CH1 = CH0 + NCH / 2;
  float* slab = blockIdx.z ? slab1 : slab0;
  f32x4 acc[4][2];
#pragma unroll
  for (int m = 0; m < 4; ++m)
#pragma unroll
    for (int n = 0; n < 2; ++n) acc[m][n] = (f32x4){0.f, 0.f, 0.f, 0.f};

  // B-row geometry (round 4): row = tid>>1, k-half = tid&1
  const int brow = tid >> 1, bhalf = tid & 1;
  const int bpx = pxT * 128 + brow;
  const int bimg = bpx >> 10, bp = bpx & 1023, bu = bp >> 5, bvc = bp & 31;

  uint4 bg[2][2], ag[2];

  auto prefetch = [&](int chunk) {
    const int tap = chunk >> 3, cg = chunk & 7;
    int iy, ix; bool bval; size_t rowb;
    if (KIND == 0) {
      int ky = tap >> 2, kx = tap & 3;
      iy = 2 * bu - 1 + ky; ix = 2 * bvc - 1 + kx;
      bval = ((unsigned)iy < 64u) && ((unsigned)ix < 64u);
      rowb = ((size_t)(bimg * 4096 + iy * 64 + ix)) << 8;
    } else {
      int ky = tap / 3, kx = tap - ky * 3;
      iy = bu - 1 + ky; ix = bvc - 1 + kx;
      bval = ((unsigned)iy < 32u) && ((unsigned)ix < 32u);
      rowb = ((size_t)(bimg * 1024 + iy * 32 + ix)) << 8;
    }
    const int koff = cg * 32 + bhalf * 16;
    if (bval) {
      bg[0][0] = *(const uint4*)(x0 + rowb + koff);
      bg[0][1] = *(const uint4*)(x0 + rowb + koff + 8);
      bg[1][0] = *(const uint4*)(x1 + rowb + koff);
      bg[1][1] = *(const uint4*)(x1 + rowb + koff + 8);
    } else {
      uint4 z; z.x = 0; z.y = 0; z.z = 0; z.w = 0;
      bg[0][0] = z; bg[0][1] = z; bg[1][0] = z; bg[1][1] = z;
    }
    const ushort_t* ap = wp + ((size_t)(chunk * 4 + coT) << 12);  // [pl][64][32]
    ag[0] = *(const uint4*)(ap + tid * 8);
    ag[1] = *(const uint4*)(ap + (tid + 256) * 8);
  };
  auto storeLDS = [&](int buf) {
    ushort_t* sAb = sA + buf * 4096;
    ushort_t* sBb = sB + buf * 8192;
    *(uint4*)(sAb + tid * 8) = ag[0];
    *(uint4*)(sAb + (tid + 256) * 8) = ag[1];
    ushort_t* bd = sBb + brow * 32 + bhalf * 16;
    *(uint4*)(bd) = bg[0][0];
    *(uint4*)(bd + 8) = bg[0][1];
    *(uint4*)(bd + 4096) = bg[1][0];
    *(uint4*)(bd + 4096 + 8) = bg[1][1];
  };

  prefetch(CH0);
  storeLDS(0);
  __syncthreads();
#pragma unroll 2
  for (int c = CH0; c < CH1; ++c) {
    const int buf = (c - CH0) & 1;
    const bool more = (c + 1 < CH1);
    if (more) prefetch(c + 1);   // in flight during MFMAs below
    const ushort_t* sAb = sA + buf * 4096;
    const ushort_t* sBb = sB + buf * 8192;
    short8 af[4][2], bf[2][2];
#pragma unroll
    for (int m = 0; m < 4; ++m)
#pragma unroll
      for (int pl = 0; pl < 2; ++pl)
        af[m][pl] = *(const short8*)(sAb + pl * 2048 + (m * 16 + l15) * 32 + q * 8);
#pragma unroll
    for (int n = 0; n < 2; ++n)
#pragma unroll
      for (int pl = 0; pl < 2; ++pl)
        bf[n][pl] = *(const short8*)(sBb + pl * 4096 + (wv * 32 + n * 16 + l15) * 32 + q * 8);
#pragma unroll
    for (int m = 0; m < 4; ++m)
#pragma unroll
      for (int n = 0; n < 2; ++n) {
        acc[m][n] = __builtin_amdgcn_mfma_f32_16x16x32_bf16(af[m][0], bf[n][0], acc[m][n], 0, 0, 0);
        acc[m][n] = __builtin_amdgcn_mfma_f32_16x16x32_bf16(af[m][0], bf[n][1], acc[m][n], 0, 0, 0);
        acc[m][n] = __builtin_amdgcn_mfma_f32_16x16x32_bf16(af[m][1], bf[n][0], acc[m][n], 0, 0, 0);
      }
    if (more) storeLDS(buf ^ 1);  // other buffer: its readers all passed last barrier
    __syncthreads();
  }
  // plain stores to this kz's slab (each element written exactly once)
#pragma unroll
  for (int m = 0; m < 4; ++m) {
#pragma unroll
    for (int n = 0; n < 2; ++n) {
#pragma unroll
      for (int r = 0; r < 4; ++r) {
        const int co_l = m * 16 + q * 4 + r;        // [0,64)
        const int px_l = wv * 32 + n * 16 + l15;    // [0,128)
        const int px = pxT * 128 + px_l;
        const int img = px >> 10, pp = px & 1023;
        const size_t ha = ((size_t)(img * 256 + coT * 64 + co_l)) * 1024 + pp;
        slab[ha] = acc[m][n][r];
      }
    }
  }
}

// ---------- conv2 epilogue 1: h32 = relu(slabA + slabB + bias), elementwise ----
// slabB occupies the h32 region itself (same index) -> in-place safe.
__global__ __launch_bounds__(256) void k_epi_sum_relu(
    const float* __restrict__ slabA, float* __restrict__ slabB_h32,
    const float* __restrict__ bias)
{
  int i = blockIdx.x * 256 + threadIdx.x;  // 2,097,152
  int co = (i >> 10) & 255;
  float v = slabA[i] + slabB_h32[i] + bias[co];
  slabB_h32[i] = fmaxf(v, 0.f);
}

// ---------- conv2 epilogue 2: split-bf16 planes from h32 ----------
__global__ __launch_bounds__(256) void k_split_h(
    const float* __restrict__ h32, ushort_t* __restrict__ s0, ushort_t* __restrict__ s1)
{
  const int px = blockIdx.x * 256 + threadIdx.x;  // 8192
  const int co0 = blockIdx.y * 16;
  const int img = px >> 10, pp = px & 1023;
  uint p0[8], p1[8];
#pragma unroll
  for (int i = 0; i < 8; ++i) {
    size_t ha = ((size_t)(img * 256 + co0 + 2 * i)) * 1024 + pp;
    float sa = h32[ha], sb = h32[ha + 1024];   // already relu'd
    ushort_t a0 = f2bf(sa), b0 = f2bf(sb);
    p0[i] = (uint)a0 | ((uint)b0 << 16);
    p1[i] = (uint)f2bf(sa - bf2f(a0)) | ((uint)f2bf(sb - bf2f(b0)) << 16);
  }
  ushort_t* d0 = s0 + (size_t)px * 256 + co0;
  ushort_t* d1 = s1 + (size_t)px * 256 + co0;
  uint4 v0a; v0a.x = p0[0]; v0a.y = p0[1]; v0a.z = p0[2]; v0a.w = p0[3];
  uint4 v0b; v0b.x = p0[4]; v0b.y = p0[5]; v0b.z = p0[6]; v0b.w = p0[7];
  uint4 v1a; v1a.x = p1[0]; v1a.y = p1[1]; v1a.z = p1[2]; v1a.w = p1[3];
  uint4 v1b; v1b.x = p1[4]; v1b.y = p1[5]; v1b.z = p1[6]; v1b.w = p1[7];
  *(uint4*)d0 = v0a; *(uint4*)(d0 + 8) = v0b;
  *(uint4*)d1 = v1a; *(uint4*)(d1 + 8) = v1b;
}

// ---------- 3x3 epilogue: spB = split(relu(slabA + slabB + bias)) ----------
__global__ __launch_bounds__(256) void k_epi3(
    const float* __restrict__ slabA, const float* __restrict__ slabB,
    const float* __restrict__ bias,
    ushort_t* __restrict__ s0, ushort_t* __restrict__ s1)
{
  const int px = blockIdx.x * 256 + threadIdx.x;  // 8192
  const int co0 = blockIdx.y * 16;
  const int img = px >> 10, pp = px & 1023;
  uint p0[8], p1[8];
#pragma unroll
  for (int i = 0; i < 8; ++i) {
    size_t ha = ((size_t)(img * 256 + co0 + 2 * i)) * 1024 + pp;
    size_t hb = ha + 1024;
    float sa = fmaxf(slabA[ha] + slabB[ha] + bias[co0 + 2 * i], 0.f);
    float sb = fmaxf(slabA[hb] + slabB[hb] + bias[co0 + 2 * i + 1], 0.f);
    ushort_t a0 = f2bf(sa), b0 = f2bf(sb);
    p0[i] = (uint)a0 | ((uint)b0 << 16);
    p1[i] = (uint)f2bf(sa - bf2f(a0)) | ((uint)f2bf(sb - bf2f(b0)) << 16);
  }
  ushort_t* d0 = s0 + (size_t)px * 256 + co0;
  ushort_t* d1 = s1 + (size_t)px * 256 + co0;
  uint4 v0a; v0a.x = p0[0]; v0a.y = p0[1]; v0a.z = p0[2]; v0a.w = p0[3];
  uint4 v0b; v0b.x = p0[4]; v0b.y = p0[5]; v0b.z = p0[6]; v0b.w = p0[7];
  uint4 v1a; v1a.x = p1[0]; v1a.y = p1[1]; v1a.z = p1[2]; v1a.w = p1[3];
  uint4 v1b; v1b.x = p1[4]; v1b.y = p1[5]; v1b.z = p1[6]; v1b.w = p1[7];
  *(uint4*)d0 = v0a; *(uint4*)(d0 + 8) = v0b;
  *(uint4*)d1 = v1a; *(uint4*)(d1 + 8) = v1b;
}

// ---------- encoder 1x1 MFMA (h += conv(spB); optional split-out) ----------
// Block 64co x 128px, 4 waves 64x32; 8 chunks; pitch-40 LDS (round-6, neutral).
template<bool WS>
__global__ __launch_bounds__(256) void k_enc_1x1(
    const ushort_t* __restrict__ x0, const ushort_t* __restrict__ x1,
    const ushort_t* __restrict__ wp, const float* __restrict__ bias,
    float* __restrict__ h32, ushort_t* __restrict__ sp0, ushort_t* __restrict__ sp1)
{
  __shared__ ushort_t smem[18432];   // sA 128*40 | sB 256*40 ; epilogue: 2x128x72
  ushort_t* sA = smem;               // [pl*64+row][k32 @40]
  ushort_t* sB = smem + 5120;        // [pl*128+row][k32 @40]
  const int tid = threadIdx.x, lane = tid & 63, wv = tid >> 6;
  const int l15 = lane & 15, q = lane >> 4;
  const int pxT = blockIdx.x, coT = blockIdx.y;
  f32x4 acc[4][2];
#pragma unroll
  for (int m = 0; m < 4; ++m)
#pragma unroll
    for (int n = 0; n < 2; ++n) acc[m][n] = (f32x4){0.f, 0.f, 0.f, 0.f};

  const int brow = tid & 127;
  const ushort_t* xb = (tid >> 7) ? x1 : x0;
  const size_t rowb = ((size_t)(pxT * 128 + brow)) << 8;

  for (int chunk = 0; chunk < 8; ++chunk) {
    uint4 bg[4], ag[2];
    const int koff = chunk * 32;
#pragma unroll
    for (int i = 0; i < 4; ++i) bg[i] = *(const uint4*)(xb + rowb + koff + i * 8);
    const ushort_t* ap = wp + ((size_t)(chunk * 4 + coT) << 12);  // [pl][64][32] = 4096
#pragma unroll
    for (int i = 0; i < 2; ++i) {
      int idx = tid + 256 * i;                 // 0..511
      ag[i] = *(const uint4*)(ap + (idx & 127) * 32 + (idx >> 7) * 8);
    }
    __syncthreads();
#pragma unroll
    for (int i = 0; i < 2; ++i) {
      int idx = tid + 256 * i;
      *(uint4*)(&sA[(idx & 127) * 40 + (idx >> 7) * 8]) = ag[i];
    }
#pragma unroll
    for (int i = 0; i < 4; ++i)
      *(uint4*)(&sB[tid * 40 + i * 8]) = bg[i];
    __syncthreads();
    short8 af[4][2], bf[2][2];
#pragma unroll
    for (int m = 0; m < 4; ++m)
#pragma unroll
      for (int pl = 0; pl < 2; ++pl)
        af[m][pl] = *(const short8*)(sA + (pl * 64 + m * 16 + l15) * 40 + q * 8);
#pragma unroll
    for (int n = 0; n < 2; ++n)
#pragma unroll
      for (int pl = 0; pl < 2; ++pl)
        bf[n][pl] = *(const short8*)(sB + (pl * 128 + wv * 32 + n * 16 + l15) * 40 + q * 8);
#pragma unroll
    for (int m = 0; m < 4; ++m)
#pragma unroll
      for (int n = 0; n < 2; ++n) {
        acc[m][n] = __builtin_amdgcn_mfma_f32_16x16x32_bf16(af[m][0], bf[n][0], acc[m][n], 0, 0, 0);
        acc[m][n] = __builtin_amdgcn_mfma_f32_16x16x32_bf16(af[m][0], bf[n][1], acc[m][n], 0, 0, 0);
        acc[m][n] = __builtin_amdgcn_mfma_f32_16x16x32_bf16(af[m][1], bf[n][0], acc[m][n], 0, 0, 0);
      }
  }
  __syncthreads();
  // epilogue: h += v (+bias); optionally split(relu(h)) via smem
#pragma unroll
  for (int m = 0; m < 4; ++m) {
#pragma unroll
    for (int n = 0; n < 2; ++n) {
#pragma unroll
      for (int r = 0; r < 4; ++r) {
        const int co_l = m * 16 + q * 4 + r;        // [0,64)
        const int px_l = wv * 32 + n * 16 + l15;    // [0,128)
        float v = acc[m][n][r] + bias[coT * 64 + co_l];
        const int px = pxT * 128 + px_l;
        const int img = px >> 10, pp = px & 1023;
        const size_t ha = ((size_t)(img * 256 + coT * 64 + co_l)) * 1024 + pp;
        v += h32[ha];
        h32[ha] = v;
        if (WS) {
          float sv = fmaxf(v, 0.f);
          ushort_t b0 = f2bf(sv);
          smem[px_l * 72 + co_l] = b0;
          smem[9216 + px_l * 72 + co_l] = f2bf(sv - bf2f(b0));
        }
      }
    }
  }
  if (WS) {
    __syncthreads();
#pragma unroll
    for (int i = 0; i < 8; ++i) {
      int idx = tid + 256 * i;
      int pl = idx >> 10, w2 = idx & 1023, pxl = w2 >> 3, g = w2 & 7;
      uint4 vv = *(const uint4*)(smem + pl * 9216 + pxl * 72 + g * 8);
      ushort_t* dst = (pl ? sp1 : sp0) + ((size_t)(pxT * 128 + pxl)) * 256 + coT * 64 + g * 8;
      *(uint4*)dst = vv;
    }
  }
}

// ---------- 1x1 conv fp32 (to_z only) ----------
__global__ __launch_bounds__(256) void k_conv1x1(
    const float* __restrict__ in, float* __restrict__ out,
    const float* __restrict__ wT, const float* __restrict__ bias,
    int CI, int CO, int P)
{
  const int p = blockIdx.x * 256 + threadIdx.x;
  const int cob = blockIdx.y * 16;
  const int n = blockIdx.z;
  const float* inN = in + (size_t)n * CI * P + p;
  float acc[16];
#pragma unroll
  for (int i = 0; i < 16; ++i) acc[i] = bias[cob + i];
  const float* wr = wT + cob;
#pragma unroll 4
  for (int ci = 0; ci < CI; ++ci) {
    float iv = inN[(size_t)ci * P];
    const float* w = wr + (size_t)ci * CO;  // uniform
#pragma unroll
    for (int i = 0; i < 16; ++i) acc[i] = fmaf(iv, w[i], acc[i]);
  }
  float* outN = out + (size_t)n * CO * P + p;
#pragma unroll
  for (int i = 0; i < 16; ++i) outN[(size_t)(cob + i) * P] = acc[i];
}

// ---------- VQ partial: 16 chunks of 32 codes ----------
__global__ __launch_bounds__(256) void k_vq_part(
    const float* __restrict__ z_e, const float* __restrict__ cb,
    const float* __restrict__ cnorm, float* __restrict__ pbest, int* __restrict__ pbid)
{
  int g = blockIdx.x * 256 + threadIdx.x;  // 8192 points
  int chunk = blockIdx.y;                  // 16 chunks
  int img = g >> 10, p = g & 1023;
  const float* zp = z_e + (size_t)img * 64 * 1024 + p;
  float z[64];
#pragma unroll
  for (int c = 0; c < 64; ++c) z[c] = zp[(size_t)c * 1024];
  float best = 3.4e38f; int bid = chunk << 5;
  const int j0 = chunk << 5;
  for (int j = j0; j < j0 + 32; ++j) {
    const float* cj = cb + j * 64;  // uniform -> scalar loads
    float m = 0.f;
#pragma unroll
    for (int c = 0; c < 64; ++c) m = fmaf(z[c], cj[c], m);
    float d = fmaf(-2.f, m, cnorm[j]);
    if (d < best) { best = d; bid = j; }  // strict <: first-min within chunk
  }
  pbest[chunk * 8192 + g] = best;
  pbid[chunk * 8192 + g] = bid;
}

// ---------- VQ reduce (ascending chunks -> np.argmin) + e_k gather ----------
__global__ __launch_bounds__(256) void k_vq_reduce(
    const float* __restrict__ pbest, const int* __restrict__ pbid,
    const float* __restrict__ cb, float* __restrict__ ids_f, float* __restrict__ ek)
{
  int g = blockIdx.x * 256 + threadIdx.x;  // 8192
  float best = 3.4e38f; int bid = 0;
#pragma unroll
  for (int ch = 0; ch < 16; ++ch) {
    float d = pbest[ch * 8192 + g];
    int b = pbid[ch * 8192 + g];
    if (d < best) { best = d; bid = b; }
  }
  ids_f[g] = (float)bid;
  int img = g >> 10, p = g & 1023;
  const float* cbid = cb + bid * 64;
  float* ekp = ek + (size_t)img * 64 * 1024 + p;
#pragma unroll
  for (int c = 0; c < 64; ++c) ekp[(size_t)c * 1024] = cbid[c];
}

// ---------- from_z 1x1 (64->256) + relu -> NHWC bf16 ----------
__global__ __launch_bounds__(256) void k_from_z(
    const float* __restrict__ ek, ushort_t* __restrict__ nhwc,
    const float* __restrict__ wT, const float* __restrict__ bias)
{
  const int p = blockIdx.x * 256 + threadIdx.x;  // 0..1023
  const int co0 = blockIdx.y * 16;
  const int n = blockIdx.z;
  const float* inN = ek + (size_t)n * 64 * 1024 + p;
  float acc[16];
#pragma unroll
  for (int i = 0; i < 16; ++i) acc[i] = bias[co0 + i];
#pragma unroll 4
  for (int ci = 0; ci < 64; ++ci) {
    float iv = inN[(size_t)ci * 1024];
    const float* w = wT + (size_t)ci * 256 + co0;  // uniform
#pragma unroll
    for (int i = 0; i < 16; ++i) acc[i] = fmaf(iv, w[i], acc[i]);
  }
  uint pk[8];
#pragma unroll
  for (int i = 0; i < 8; ++i) {
    ushort_t lo = f2bf(fmaxf(acc[2 * i], 0.f));
    ushort_t hi = f2bf(fmaxf(acc[2 * i + 1], 0.f));
    pk[i] = (uint)lo | ((uint)hi << 16);
  }
  ushort_t* op = nhwc + (((size_t)n * 1024 + p) * 256 + co0);
  uint4 v0; v0.x = pk[0]; v0.y = pk[1]; v0.z = pk[2]; v0.w = pk[3];
  uint4 v1; v1.x = pk[4]; v1.y = pk[5]; v1.z = pk[6]; v1.w = pk[7];
  *(uint4*)(op) = v0;
  *(uint4*)(op + 8) = v1;
}

// ---------- t1 convtranspose 4x4 s2 p1, 256->256, bf16 MFMA -> bf16 NHWC ----
__global__ __launch_bounds__(256) void k_mfma_t1(
    const ushort_t* __restrict__ nhwc, const ushort_t* __restrict__ wb,
    const float* __restrict__ bias, ushort_t* __restrict__ t1o)
{
  __shared__ ushort_t sA[128 * 40];
  __shared__ ushort_t sB[128 * 40];
  const int tid = threadIdx.x;
  const int lane = tid & 63;
  const int wv = tid >> 6;
  const int wm = wv & 1, wn = wv >> 1;
  const int l15 = lane & 15, q = lane >> 4;
  const int pxT = blockIdx.x, coT = blockIdx.y, par = blockIdx.z;
  const int ry = par & 1, rx = (par >> 1) & 1;
  const int pxbase = pxT * 128;
  const int img = pxbase >> 10;
  f32x4 acc[4][4];
#pragma unroll
  for (int i = 0; i < 4; ++i)
#pragma unroll
    for (int j = 0; j < 4; ++j) acc[i][j] = (f32x4){0.f, 0.f, 0.f, 0.f};

  for (int c = 0; c < 32; ++c) {
    const int tap = c >> 3, c8 = c & 7;
    const int a = tap >> 1, b = tap & 1;
    const ushort_t* Abase = wb + ((size_t)((par * 4 + tap) * 8 + c8) << 13);
    uint4 av[2], bvv[2];
#pragma unroll
    for (int r = 0; r < 2; ++r) {
      int idx = tid + 256 * r;             // 0..511
      int row = idx & 127, kg = idx >> 7;  // kg 0..3
      av[r] = *(const uint4*)(Abase + ((coT * 128 + row) * 32 + kg * 8));
      int px = pxbase + row;
      int u = (px >> 5) & 31, vv = px & 31;
      int iy = u + ry - a, ix = vv + rx - b;
      if ((unsigned)iy < 32u && (unsigned)ix < 32u)
        bvv[r] = *(const uint4*)(nhwc + ((size_t)(img * 1024 + iy * 32 + ix) * 256 + c8 * 32 + kg * 8));
      else { bvv[r].x = 0u; bvv[r].y = 0u; bvv[r].z = 0u; bvv[r].w = 0u; }
    }
    __syncthreads();
#pragma unroll
    for (int r = 0; r < 2; ++r) {
      int idx = tid + 256 * r;
      int row = idx & 127, kg = idx >> 7;
      *(uint4*)(&sA[row * 40 + kg * 8]) = av[r];
      *(uint4*)(&sB[row * 40 + kg * 8]) = bvv[r];
    }
    __syncthreads();
    short8 af[4], bfr[4];
#pragma unroll
    for (int i = 0; i < 4; ++i)
      af[i] = *(const short8*)(sA + (wm * 64 + i * 16 + l15) * 40 + q * 8);
#pragma unroll
    for (int j = 0; j < 4; ++j)
      bfr[j] = *(const short8*)(sB + (wn * 64 + j * 16 + l15) * 40 + q * 8);
#pragma unroll
    for (int i = 0; i < 4; ++i)
#pragma unroll
      for (int j = 0; j < 4; ++j)
        acc[i][j] = __builtin_amdgcn_mfma_f32_16x16x32_bf16(af[i], bfr[j], acc[i][j], 0, 0, 0);
  }
#pragma unroll
  for (int i = 0; i < 4; ++i) {
    int co = coT * 128 + wm * 64 + i * 16 + q * 4;
#pragma unroll
    for (int j = 0; j < 4; ++j) {
      int px = pxbase + wn * 64 + j * 16 + l15;
      int u = (px >> 5) & 31, vv = px & 31;
      int oy = 2 * u + ry, ox = 2 * vv + rx;
      ushort_t e0 = f2bf(fmaxf(acc[i][j][0] + bias[co + 0], 0.f));
      ushort_t e1 = f2bf(fmaxf(acc[i][j][1] + bias[co + 1], 0.f));
      ushort_t e2 = f2bf(fmaxf(acc[i][j][2] + bias[co + 2], 0.f));
      ushort_t e3 = f2bf(fmaxf(acc[i][j][3] + bias[co + 3], 0.f));
      uint2 pk; pk.x = (uint)e0 | ((uint)e1 << 16); pk.y = (uint)e2 | ((uint)e3 << 16);
      *(uint2*)(t1o + ((size_t)(img * 4096 + oy * 64 + ox) * 256 + co)) = pk;
    }
  }
}

// ---------- t2 convtranspose 4x4 s2 p1, 256->3, bf16 MFMA, sigmoid ----------
__global__ __launch_bounds__(256) void k_mfma_t2(
    const ushort_t* __restrict__ t1o, const ushort_t* __restrict__ wb,
    const float* __restrict__ bias, float* __restrict__ out)
{
  __shared__ ushort_t sA2[256 * 40];
  __shared__ ushort_t sB2[16 * 40];
  const int tid = threadIdx.x, lane = tid & 63, wv = tid >> 6;
  const int l15 = lane & 15, q = lane >> 4;
  const int pxb = blockIdx.x * 256;
  const int par = blockIdx.y;
  const int ry = par & 1, rx = (par >> 1) & 1;
  f32x4 acc[4];
#pragma unroll
  for (int m = 0; m < 4; ++m) acc[m] = (f32x4){0.f, 0.f, 0.f, 0.f};
  const int px = pxb + tid;
  const int pimg = px >> 12, pp = px & 4095, pu = pp >> 6, pv = pp & 63;
  size_t rb = 0; bool rv = false;
  for (int chunk = 0; chunk < 32; ++chunk) {
    const int tap = chunk >> 3, cg = chunk & 7;
    if ((chunk & 7) == 0) {
      const int a = tap >> 1, b = tap & 1;
      int iy = pu + ry - a, ix = pv + rx - b;
      rv = ((unsigned)iy < 64u) && ((unsigned)ix < 64u);
      rb = ((size_t)(pimg * 4096 + iy * 64 + ix)) << 8;
    }
    uint4 av[4];
#pragma unroll
    for (int kg = 0; kg < 4; ++kg) {
      if (rv) av[kg] = *(const uint4*)(t1o + rb + cg * 32 + kg * 8);
      else { av[kg].x = 0; av[kg].y = 0; av[kg].z = 0; av[kg].w = 0; }
    }
    uint4 bv;
    if (tid < 64) {
      int co = tid & 15, kgb = tid >> 4;
      bv = *(const uint4*)(wb + ((size_t)(par * 32 + chunk) * 16 + co) * 32 + kgb * 8);
    }
    __syncthreads();
#pragma unroll
    for (int kg = 0; kg < 4; ++kg)
      *(uint4*)(&sA2[tid * 40 + kg * 8]) = av[kg];
    if (tid < 64) {
      int co = tid & 15, kgb = tid >> 4;
      *(uint4*)(&sB2[co * 40 + kgb * 8]) = bv;
    }
    __syncthreads();
    short8 bf = *(const short8*)(sB2 + l15 * 40 + q * 8);
#pragma unroll
    for (int m = 0; m < 4; ++m) {
      short8 af = *(const short8*)(sA2 + (wv * 64 + m * 16 + l15) * 40 + q * 8);
      acc[m] = __builtin_amdgcn_mfma_f32_16x16x32_bf16(af, bf, acc[m], 0, 0, 0);
    }
    __syncthreads();
  }
  const int co = l15;
  if (co < 3) {
    float bco = bias[co];
#pragma unroll
    for (int m = 0; m < 4; ++m) {
#pragma unroll
      for (int r = 0; r < 4; ++r) {
        int opx = pxb + wv * 64 + m * 16 + q * 4 + r;
        int img = opx >> 12, p = opx & 4095, u = p >> 6, v = p & 63;
        size_t addr = ((size_t)(img * 3 + co)) * 16384 + (2 * u + ry) * 128 + (2 * v + rx);
        out[addr] = 1.f / (1.f + expf(-(acc[m][r] + bco)));
      }
    }
  }
}

// ---------------------------------------------------------------------------
extern "C" void kernel_launch(void* const* d_in, const int* in_sizes, int n_in,
                              void* d_out, int out_size, void* d_ws, size_t ws_size,
                              hipStream_t stream) {
  (void)in_sizes; (void)n_in; (void)out_size; (void)ws_size;
  const float* x      = (const float*)d_in[0];
  const float* c1_w   = (const float*)d_in[1];
  const float* c1_b   = (const float*)d_in[2];
  const float* c2_w   = (const float*)d_in[3];
  const float* c2_b   = (const float*)d_in[4];
  const float* r0_w3  = (const float*)d_in[5];
  const float* r0_b3  = (const float*)d_in[6];
  const float* r0_w1  = (const float*)d_in[7];
  const float* r0_b1  = (const float*)d_in[8];
  const float* r1_w3  = (const float*)d_in[9];
  const float* r1_b3  = (const float*)d_in[10];
  const float* r1_w1  = (const float*)d_in[11];
  const float* r1_b1  = (const float*)d_in[12];
  const float* to_z_w = (const float*)d_in[13];
  const float* to_z_b = (const float*)d_in[14];
  const float* cb     = (const float*)d_in[15];
  const float* from_z_w = (const float*)d_in[16];
  const float* from_z_b = (const float*)d_in[17];
  const float* t1_w   = (const float*)d_in[18];
  const float* t1_b   = (const float*)d_in[19];
  const float* t2_w   = (const float*)d_in[20];
  const float* t2_b   = (const float*)d_in[21];

  float* wsf = (float*)d_ws;
  // era-overlapped regions (float offsets):
  ushort_t* xs1p0 = (ushort_t*)(wsf + 0);        // conv1-era [0, 4.19M)
  ushort_t* xs1p1 = (ushort_t*)(wsf + 4194304);  // conv1-era [4.19M, 8.39M)
  ushort_t* spB0  = (ushort_t*)(wsf + 0);        // res-era   [0, 1.05M)
  ushort_t* spB1  = (ushort_t*)(wsf + 1048576);  // res-era   [1.05M, 2.1M)
  float*    pbest = wsf + 0;                     // vq-era
  int*      pbid  = (int*)(wsf + 131072);        // vq-era
  float*    slabC = wsf + 2097152;               // 3x3-era [2.1M, 4.19M)
  float*    slabD = wsf + 4194304;               // 3x3-era [4.19M, 6.29M)
  ushort_t* t1out = (ushort_t*)(wsf + 2097152);  // dec-era [2.1M, 6.29M)
  ushort_t* decn  = (ushort_t*)(wsf + 6291456);  // dec-era [6.29M, 7.34M)
  float*    h32   = wsf + 8388608;               // [8.39M, 10.49M); conv2 slabB (in-place)
  float*    slabA = wsf + 10485760;              // conv2-era; becomes spA region after epi1
  ushort_t* spA0  = (ushort_t*)(wsf + 10485760);
  ushort_t* spA1  = (ushort_t*)(wsf + 11534336);
  ushort_t* wp_c2   = (ushort_t*)(wsf + 12582912);
  ushort_t* wp_r0w3 = (ushort_t*)(wsf + 13631488);
  ushort_t* wp_r1w3 = (ushort_t*)(wsf + 14221312);
  ushort_t* wp_r0w1 = (ushort_t*)(wsf + 14811136);
  ushort_t* wp_r1w1 = (ushort_t*)(wsf + 14876672);
  float*    wt_c1   = wsf + 14942208;
  float*    wt_toz  = wsf + 14954496;
  float*    wt_fromz= wsf + 14970880;
  ushort_t* t1wb    = (ushort_t*)(wsf + 14987264);
  ushort_t* w2pk    = (ushort_t*)(wsf + 15511552);
  float*    cnorm   = wsf + 15544320;

  float* out_img = (float*)d_out;        // 393216
  float* z_e_out = out_img + 393216;     // 524288
  float* e_k_out = z_e_out + 524288;     // 524288
  float* ids_out = e_k_out + 524288;     // 8192 (stored as float)

  // ---- weight prep ----
  k_transpose_w<<<48, 256, 0, stream>>>(c1_w, wt_c1, 256, 48);
  k_transpose_w<<<64, 256, 0, stream>>>(to_z_w, wt_toz, 64, 256);
  k_transpose_w<<<64, 256, 0, stream>>>(from_z_w, wt_fromz, 256, 64);
  k_prep_enc<0><<<8192, 256, 0, stream>>>(c2_w,  wp_c2,   128 << 14);
  k_prep_enc<1><<<4608, 256, 0, stream>>>(r0_w3, wp_r0w3, 72 << 14);
  k_prep_enc<1><<<4608, 256, 0, stream>>>(r1_w3, wp_r1w3, 72 << 14);
  k_prep_enc<2><<<512,  256, 0, stream>>>(r0_w1, wp_r0w1, 8 << 14);
  k_prep_enc<2><<<512,  256, 0, stream>>>(r1_w1, wp_r1w1, 8 << 14);
  k_prep_t1w<<<4096, 256, 0, stream>>>(t1_w, t1wb);
  k_prep_t2w<<<256, 256, 0, stream>>>(t2_w, w2pk);
  k_prep_cb<<<2, 256, 0, stream>>>(cb, cnorm);

  // ---- encoder ----
  k_conv1_split<<<dim3(64, 4, 8), 256, 0, stream>>>(x, xs1p0, xs1p1, wt_c1, c1_b);
  // conv2: split-K=2 -> slabA + slabB(=h32 region); epi1 sums elementwise; epi2 splits
  k_enc_mfma_split<0><<<dim3(64, 4, 2), 256, 0, stream>>>(xs1p0, xs1p1, wp_c2, slabA, h32);
  k_epi_sum_relu<<<8192, 256, 0, stream>>>(slabA, h32, c2_b);
  k_split_h<<<dim3(32, 16), 256, 0, stream>>>(h32, spA0, spA1);
  // r0 w3: split-K=2 -> slabC/D (conv1-output region, dead); epi3 -> spB
  k_enc_mfma_split<1><<<dim3(64, 4, 2), 256, 0, stream>>>(spA0, spA1, wp_r0w3, slabC, slabD);
  k_epi3<<<dim3(32, 16), 256, 0, stream>>>(slabC, slabD, r0_b3, spB0, spB1);
  // r0 w1: h += conv; write h32 + split(relu(h)) -> spA
  k_enc_1x1<true><<<dim3(64, 4), 256, 0, stream>>>(spB0, spB1, wp_r0w1, r0_b1, h32, spA0, spA1);
  // r1 w3
  k_enc_mfma_split<1><<<dim3(64, 4, 2), 256, 0, stream>>>(spA0, spA1, wp_r1w3, slabC, slabD);
  k_epi3<<<dim3(32, 16), 256, 0, stream>>>(slabC, slabD, r1_b3, spB0, spB1);
  // r1 w1: h += conv; write h32 only
  k_enc_1x1<false><<<dim3(64, 4), 256, 0, stream>>>(spB0, spB1, wp_r1w1, r1_b1, h32, nullptr, nullptr);
  // to_z (fp32)
  k_conv1x1<<<dim3(4, 4, 8), 256, 0, stream>>>(h32, z_e_out, wt_toz, to_z_b, 256, 64, 1024);

  // ---- VQ (chunk-parallel; bit-identical argmin) ----
  k_vq_part<<<dim3(32, 16), 256, 0, stream>>>(z_e_out, cb, cnorm, pbest, pbid);
  k_vq_reduce<<<32, 256, 0, stream>>>(pbest, pbid, cb, ids_out, e_k_out);

  // ---- decoder (bf16) ----
  k_from_z<<<dim3(4, 16, 8), 256, 0, stream>>>(e_k_out, decn, wt_fromz, from_z_b);
  k_mfma_t1<<<dim3(64, 2, 4), 256, 0, stream>>>(decn, t1wb, t1_b, t1out);
  k_mfma_t2<<<dim3(128, 4), 256, 0, stream>>>(t1out, w2pk, t2_b, out_img);
}

// Round 9
// 572.285 us; speedup vs baseline: 1.2702x; 1.1149x over previous
//
#include <hip/hip_runtime.h>
#include <math.h>

// ---------------------------------------------------------------------------
// VQ-VAE forward.
// Encoder: 256-ch convs as implicit-GEMM MFMA with 2-term bf16 split inputs
// (3 passes: w1x1 + w1x2 + w2x1). Big convs: ROUND-4 loop byte-for-byte
// (64co x 128px blocks, 24KB pitch-32 LDS, paired B-row loads -- 82us
// measured), atomicAdd tail swapped for per-kz slab stores + fixed-order
// epilogue reduce. conv2 kz=2; 3x3 kz=3 (768 blocks = 3/CU grid-cap test).
// NOTE (r8 post-mortem): conv2 epilogue MUST be two kernels -- the fused
// version wrote spA (aliasing slabA) while other blocks still read slabA.
// VQ: chunk-parallel partial argmin + reduce; bit-identical to serial.
// ---------------------------------------------------------------------------

typedef unsigned int uint;
typedef unsigned short ushort_t;
using short8 = __attribute__((ext_vector_type(8))) short;
using f32x4  = __attribute__((ext_vector_type(4))) float;

static __device__ __forceinline__ ushort_t f2bf(float f) {
  uint u = __float_as_uint(f);
  return (ushort_t)((u + 0x7fffu + ((u >> 16) & 1u)) >> 16);  // RNE; finite inputs
}
static __device__ __forceinline__ float bf2f(ushort_t b) {
  return __uint_as_float(((uint)b) << 16);
}

// ---------- weight prep ----------
__global__ void k_transpose_w(const float* __restrict__ w, float* __restrict__ wT, int CO, int CIKK) {
  int idx = blockIdx.x * 256 + threadIdx.x;
  if (idx >= CO * CIKK) return;
  int co = idx % CO, i = idx / CO;
  wT[idx] = w[co * CIKK + i];
}

// encoder MFMA weight pack: w[co][ci(256)][KH][KW] fp32 ->
// wp[chunk][coT(4)][pl(2)][row(64)][k(32)] bf16 split, chunk = tap*8 + cg
template<int KIND>  // 0: 4x4 (16 taps), 1: 3x3 (9 taps), 2: 1x1 (1 tap)
__global__ void k_prep_enc(const float* __restrict__ w, ushort_t* __restrict__ wp, int total) {
  int idx = blockIdx.x * 256 + threadIdx.x;
  if (idx >= total) return;
  int k = idx & 31, row = (idx >> 5) & 63, pl = (idx >> 11) & 1, coT = (idx >> 12) & 3, chunk = idx >> 14;
  int tap = chunk >> 3, cg = chunk & 7;
  int co = coT * 64 + row, ci = cg * 32 + k;
  int ky, kx, KK, KW;
  if (KIND == 0)      { ky = tap >> 2; kx = tap & 3;       KK = 16; KW = 4; }
  else if (KIND == 1) { ky = tap / 3;  kx = tap - ky * 3;  KK = 9;  KW = 3; }
  else                { ky = 0;        kx = 0;             KK = 1;  KW = 1; }
  float v = w[(co * 256 + ci) * KK + ky * KW + kx];
  ushort_t b0 = f2bf(v);
  wp[idx] = pl ? f2bf(v - bf2f(b0)) : b0;
}

// t1_w [ci][co][ky][kx] -> bf16 [par][tap][c8][co][kk32]
__global__ void k_prep_t1w(const float* __restrict__ w, ushort_t* __restrict__ wb) {
  int idx = blockIdx.x * 256 + threadIdx.x;  // 1048576
  int kk  = idx & 31;
  int co  = (idx >> 5) & 255;
  int c8  = (idx >> 13) & 7;
  int tap = (idx >> 16) & 3;
  int par = idx >> 18;
  int ry = par & 1, rx = (par >> 1) & 1;
  int a = tap >> 1, b = tap & 1;
  int ky = ((ry + 1) & 1) + 2 * a;
  int kx = ((rx + 1) & 1) + 2 * b;
  int ci = c8 * 32 + kk;
  wb[idx] = f2bf(w[((ci * 256 + co) << 4) + ky * 4 + kx]);
}

// t2_w [ci(256)][co(3)][4][4] -> bf16 [par(4)][chunk(32)][co16][k32]
__global__ void k_prep_t2w(const float* __restrict__ w, ushort_t* __restrict__ wb) {
  int idx = blockIdx.x * 256 + threadIdx.x;  // 65536
  int k = idx & 31, co = (idx >> 5) & 15, chunk = (idx >> 9) & 31, par = idx >> 14;
  int tap = chunk >> 3, cg = chunk & 7;
  int a = tap >> 1, b = tap & 1;
  int ry = par & 1, rx = (par >> 1) & 1;
  int ky = ((ry + 1) & 1) + 2 * a;
  int kx = ((rx + 1) & 1) + 2 * b;
  int ci = cg * 32 + k;
  float v = (co < 3) ? w[((ci * 3 + co) << 4) + ky * 4 + kx] : 0.f;
  wb[idx] = f2bf(v);
}

// cnorm[j] = sum_c cb[j][c]^2
__global__ void k_prep_cb(const float* __restrict__ cb, float* __restrict__ cnorm) {
  int idx = blockIdx.x * 256 + threadIdx.x;
  if (idx < 512) {
    float s = 0.f;
    for (int c = 0; c < 64; ++c) { float v = cb[idx * 64 + c]; s = fmaf(v, v, s); }
    cnorm[idx] = s;
  }
}

// ---------- conv1: 3->256, 4x4 s2 p1, relu, output split-bf16 NHWC ----------
__global__ __launch_bounds__(256) void k_conv1_split(
    const float* __restrict__ in, ushort_t* __restrict__ o0, ushort_t* __restrict__ o1,
    const float* __restrict__ wT, const float* __restrict__ bias)
{
  __shared__ float s_in[3 * 360];  // parity-split cols, pitch 20 (2-way free)
  const int tid = threadIdx.x;
  const int lane = tid & 63;
  const int wv = __builtin_amdgcn_readfirstlane(tid >> 6);
  const int px = lane & 7, py = lane >> 3;
  const int tx = blockIdx.x & 7, ty = blockIdx.x >> 3;
  const int X = tx * 8, Y = ty * 8;
  const int cob = blockIdx.y * 64 + wv * 16;
  const int n = blockIdx.z;
  float acc[16];
#pragma unroll
  for (int i = 0; i < 16; ++i) acc[i] = bias[cob + i];
  const float* inN = in + (size_t)n * 3 * 16384;
  for (int e = tid; e < 3 * 360; e += 256) {
    int col2 = e % 20; int t = e / 20; int row = t % 18; int ci = t / 18;
    int pr = col2 / 10, hc = col2 % 10, ixl = 2 * hc + pr;
    int iy = 2 * Y - 1 + row, ix = 2 * X - 1 + ixl;
    float v = 0.f;
    if (ixl < 18 && (unsigned)iy < 128u && (unsigned)ix < 128u)
      v = inN[ci * 16384 + iy * 128 + ix];
    s_in[e] = v;
  }
  __syncthreads();
  const float* wc = wT + cob;
#pragma unroll
  for (int c = 0; c < 3; ++c) {
    const float* base = s_in + c * 360 + py * 40 + px;
#pragma unroll
    for (int ky = 0; ky < 4; ++ky) {
#pragma unroll
      for (int kx = 0; kx < 4; ++kx) {
        float iv = base[ky * 20 + (kx & 1) * 10 + (kx >> 1)];
        const float* w = wc + (size_t)(c * 16 + ky * 4 + kx) * 256;  // uniform
#pragma unroll
        for (int i = 0; i < 16; ++i) acc[i] = fmaf(iv, w[i], acc[i]);
      }
    }
  }
  const int pxg = n * 4096 + (Y + py) * 64 + (X + px);
  uint p0[8], p1[8];
#pragma unroll
  for (int i = 0; i < 8; ++i) {
    float va = fmaxf(acc[2 * i], 0.f), vb = fmaxf(acc[2 * i + 1], 0.f);
    ushort_t a0 = f2bf(va), b0 = f2bf(vb);
    ushort_t a1 = f2bf(va - bf2f(a0)), b1 = f2bf(vb - bf2f(b0));
    p0[i] = (uint)a0 | ((uint)b0 << 16);
    p1[i] = (uint)a1 | ((uint)b1 << 16);
  }
  ushort_t* d0 = o0 + (size_t)pxg * 256 + cob;
  ushort_t* d1 = o1 + (size_t)pxg * 256 + cob;
  uint4 v0a; v0a.x = p0[0]; v0a.y = p0[1]; v0a.z = p0[2]; v0a.w = p0[3];
  uint4 v0b; v0b.x = p0[4]; v0b.y = p0[5]; v0b.z = p0[6]; v0b.w = p0[7];
  uint4 v1a; v1a.x = p1[0]; v1a.y = p1[1]; v1a.z = p1[2]; v1a.w = p1[3];
  uint4 v1b; v1b.x = p1[4]; v1b.y = p1[5]; v1b.z = p1[6]; v1b.w = p1[7];
  *(uint4*)d0 = v0a; *(uint4*)(d0 + 8) = v0b;
  *(uint4*)d1 = v1a; *(uint4*)(d1 + 8) = v1b;
}

// ---------- encoder split-K MFMA: round-4 loop (82us measured), slab tail ----
// Block 64co x 128px, 4 waves of 64x32; grid (pxT 64, coT 4, kz KZ).
// Each kz writes its own slab (plain stores, full coverage -> no memset).
template<int KIND, int KZ>  // KIND 0: conv2 (128 chunks), 1: 3x3 (72 chunks)
__global__ __launch_bounds__(256) void k_enc_mfma_split(
    const ushort_t* __restrict__ x0, const ushort_t* __restrict__ x1,
    const ushort_t* __restrict__ wp, float* __restrict__ s0,
    float* __restrict__ s1, float* __restrict__ s2)
{
  __shared__ ushort_t smem[12288];   // sA 4096 | sB 8192 (ushorts, pitch 32)
  ushort_t* sA = smem;               // [pl][row64][k32]
  ushort_t* sB = smem + 4096;        // [pl][row128][k32]
  const int tid = threadIdx.x, lane = tid & 63, wv = tid >> 6;
  const int l15 = lane & 15, q = lane >> 4;
  const int pxT = blockIdx.x, coT = blockIdx.y;
  constexpr int NCH = (KIND == 0) ? 128 : 72;
  const int CH0 = blockIdx.z * (NCH / KZ), CH1 = CH0 + NCH / KZ;
  float* slab = (blockIdx.z == 0) ? s0 : ((blockIdx.z == 1) ? s1 : s2);
  f32x4 acc[4][2];
#pragma unroll
  for (int m = 0; m < 4; ++m)
#pragma unroll
    for (int n = 0; n < 2; ++n) acc[m][n] = (f32x4){0.f, 0.f, 0.f, 0.f};

  // B-row geometry: row = tid>>1, k-half = tid&1
  const int brow = tid >> 1, bhalf = tid & 1;
  const int bpx = pxT * 128 + brow;
  const int bimg = bpx >> 10, bp = bpx & 1023, bu = bp >> 5, bvc = bp & 31;
  int ptap = -1; size_t rowb = 0; bool bval = false;

  for (int chunk = CH0; chunk < CH1; ++chunk) {
    const int tap = chunk >> 3, cg = chunk & 7;
    if (tap != ptap) {
      ptap = tap;
      int ky, kx, iy, ix;
      if (KIND == 0) {
        ky = tap >> 2; kx = tap & 3;
        iy = 2 * bu - 1 + ky; ix = 2 * bvc - 1 + kx;
        bval = ((unsigned)iy < 64u) && ((unsigned)ix < 64u);
        rowb = ((size_t)(bimg * 4096 + iy * 64 + ix)) << 8;
      } else {
        ky = tap / 3; kx = tap - ky * 3;
        iy = bu - 1 + ky; ix = bvc - 1 + kx;
        bval = ((unsigned)iy < 32u) && ((unsigned)ix < 32u);
        rowb = ((size_t)(bimg * 1024 + iy * 32 + ix)) << 8;
      }
    }
    // global loads before barrier (overlap with previous MFMA tail)
    uint4 bg[2][2];
    const int koff = cg * 32 + bhalf * 16;
    if (bval) {
      bg[0][0] = *(const uint4*)(x0 + rowb + koff);
      bg[0][1] = *(const uint4*)(x0 + rowb + koff + 8);
      bg[1][0] = *(const uint4*)(x1 + rowb + koff);
      bg[1][1] = *(const uint4*)(x1 + rowb + koff + 8);
    } else {
      uint4 z; z.x = 0; z.y = 0; z.z = 0; z.w = 0;
      bg[0][0] = z; bg[0][1] = z; bg[1][0] = z; bg[1][1] = z;
    }
    const ushort_t* ap = wp + ((size_t)(chunk * 4 + coT) << 12);  // [pl][64][32] = 4096 elems
    uint4 av0 = *(const uint4*)(ap + tid * 8);
    uint4 av1 = *(const uint4*)(ap + (tid + 256) * 8);
    __syncthreads();
    *(uint4*)(sA + tid * 8) = av0;
    *(uint4*)(sA + (tid + 256) * 8) = av1;
    ushort_t* bd = sB + brow * 32 + bhalf * 16;
    *(uint4*)(bd) = bg[0][0];
    *(uint4*)(bd + 8) = bg[0][1];
    *(uint4*)(bd + 4096) = bg[1][0];
    *(uint4*)(bd + 4096 + 8) = bg[1][1];
    __syncthreads();
    short8 af[4][2], bf[2][2];
#pragma unroll
    for (int m = 0; m < 4; ++m)
#pragma unroll
      for (int pl = 0; pl < 2; ++pl)
        af[m][pl] = *(const short8*)(sA + pl * 2048 + (m * 16 + l15) * 32 + q * 8);
#pragma unroll
    for (int n = 0; n < 2; ++n)
#pragma unroll
      for (int pl = 0; pl < 2; ++pl)
        bf[n][pl] = *(const short8*)(sB + pl * 4096 + (wv * 32 + n * 16 + l15) * 32 + q * 8);
#pragma unroll
    for (int m = 0; m < 4; ++m)
#pragma unroll
      for (int n = 0; n < 2; ++n) {
        acc[m][n] = __builtin_amdgcn_mfma_f32_16x16x32_bf16(af[m][0], bf[n][0], acc[m][n], 0, 0, 0);
        acc[m][n] = __builtin_amdgcn_mfma_f32_16x16x32_bf16(af[m][0], bf[n][1], acc[m][n], 0, 0, 0);
        acc[m][n] = __builtin_amdgcn_mfma_f32_16x16x32_bf16(af[m][1], bf[n][0], acc[m][n], 0, 0, 0);
      }
  }
  // plain stores to this kz's slab (each element written exactly once)
#pragma unroll
  for (int m = 0; m < 4; ++m) {
#pragma unroll
    for (int n = 0; n < 2; ++n) {
#pragma unroll
      for (int r = 0; r < 4; ++r) {
        const int co_l = m * 16 + q * 4 + r;        // [0,64)
        const int px_l = wv * 32 + n * 16 + l15;    // [0,128)
        const int px = pxT * 128 + px_l;
        const int img = px >> 10, pp = px & 1023;
        const size_t ha = ((size_t)(img * 256 + coT * 64 + co_l)) * 1024 + pp;
        slab[ha] = acc[m][n][r];
      }
    }
  }
}

// ---------- conv2 epilogue 1: h32 = relu(slabA + slabB + bias), elementwise ----
// slabB occupies the h32 region itself (same index, same thread) -> in-place.
// MUST complete before k_split_h writes the spA region (aliases slabA).
__global__ __launch_bounds__(256) void k_epi_sum_relu(
    const float* __restrict__ slabA, float* __restrict__ slabB_h32,
    const float* __restrict__ bias)
{
  int i = blockIdx.x * 256 + threadIdx.x;  // 2,097,152
  int co = (i >> 10) & 255;
  float v = slabA[i] + slabB_h32[i] + bias[co];
  slabB_h32[i] = fmaxf(v, 0.f);
}

// ---------- conv2 epilogue 2: split-bf16 planes from h32 ----------
__global__ __launch_bounds__(256) void k_split_h(
    const float* __restrict__ h32, ushort_t* __restrict__ s0, ushort_t* __restrict__ s1)
{
  const int px = blockIdx.x * 256 + threadIdx.x;  // 8192
  const int co0 = blockIdx.y * 16;
  const int img = px >> 10, pp = px & 1023;
  uint p0[8], p1[8];
#pragma unroll
  for (int i = 0; i < 8; ++i) {
    size_t ha = ((size_t)(img * 256 + co0 + 2 * i)) * 1024 + pp;
    float sa = h32[ha], sb = h32[ha + 1024];   // already relu'd
    ushort_t a0 = f2bf(sa), b0 = f2bf(sb);
    p0[i] = (uint)a0 | ((uint)b0 << 16);
    p1[i] = (uint)f2bf(sa - bf2f(a0)) | ((uint)f2bf(sb - bf2f(b0)) << 16);
  }
  ushort_t* d0 = s0 + (size_t)px * 256 + co0;
  ushort_t* d1 = s1 + (size_t)px * 256 + co0;
  uint4 v0a; v0a.x = p0[0]; v0a.y = p0[1]; v0a.z = p0[2]; v0a.w = p0[3];
  uint4 v0b; v0b.x = p0[4]; v0b.y = p0[5]; v0b.z = p0[6]; v0b.w = p0[7];
  uint4 v1a; v1a.x = p1[0]; v1a.y = p1[1]; v1a.z = p1[2]; v1a.w = p1[3];
  uint4 v1b; v1b.x = p1[4]; v1b.y = p1[5]; v1b.z = p1[6]; v1b.w = p1[7];
  *(uint4*)d0 = v0a; *(uint4*)(d0 + 8) = v0b;
  *(uint4*)d1 = v1a; *(uint4*)(d1 + 8) = v1b;
}

// ---------- 3x3 epilogue: spB = split(relu(A+B+C+bias)) (fixed order) ----------
__global__ __launch_bounds__(256) void k_epi3(
    const float* __restrict__ slabA, const float* __restrict__ slabB,
    const float* __restrict__ slabC, const float* __restrict__ bias,
    ushort_t* __restrict__ s0, ushort_t* __restrict__ s1)
{
  const int px = blockIdx.x * 256 + threadIdx.x;  // 8192
  const int co0 = blockIdx.y * 16;
  const int img = px >> 10, pp = px & 1023;
  uint p0[8], p1[8];
#pragma unroll
  for (int i = 0; i < 8; ++i) {
    size_t ha = ((size_t)(img * 256 + co0 + 2 * i)) * 1024 + pp;
    size_t hb = ha + 1024;
    float sa = fmaxf(((slabA[ha] + slabB[ha]) + slabC[ha]) + bias[co0 + 2 * i], 0.f);
    float sb = fmaxf(((slabA[hb] + slabB[hb]) + slabC[hb]) + bias[co0 + 2 * i + 1], 0.f);
    ushort_t a0 = f2bf(sa), b0 = f2bf(sb);
    p0[i] = (uint)a0 | ((uint)b0 << 16);
    p1[i] = (uint)f2bf(sa - bf2f(a0)) | ((uint)f2bf(sb - bf2f(b0)) << 16);
  }
  ushort_t* d0 = s0 + (size_t)px * 256 + co0;
  ushort_t* d1 = s1 + (size_t)px * 256 + co0;
  uint4 v0a; v0a.x = p0[0]; v0a.y = p0[1]; v0a.z = p0[2]; v0a.w = p0[3];
  uint4 v0b; v0b.x = p0[4]; v0b.y = p0[5]; v0b.z = p0[6]; v0b.w = p0[7];
  uint4 v1a; v1a.x = p1[0]; v1a.y = p1[1]; v1a.z = p1[2]; v1a.w = p1[3];
  uint4 v1b; v1b.x = p1[4]; v1b.y = p1[5]; v1b.z = p1[6]; v1b.w = p1[7];
  *(uint4*)d0 = v0a; *(uint4*)(d0 + 8) = v0b;
  *(uint4*)d1 = v1a; *(uint4*)(d1 + 8) = v1b;
}

// ---------- encoder 1x1 MFMA (h += conv(spB); optional split-out) ----------
template<bool WS>
__global__ __launch_bounds__(256) void k_enc_1x1(
    const ushort_t* __restrict__ x0, const ushort_t* __restrict__ x1,
    const ushort_t* __restrict__ wp, const float* __restrict__ bias,
    float* __restrict__ h32, ushort_t* __restrict__ sp0, ushort_t* __restrict__ sp1)
{
  __shared__ ushort_t smem[18432];   // sA 128*40 | sB 256*40 ; epilogue: 2x128x72
  ushort_t* sA = smem;               // [pl*64+row][k32 @40]
  ushort_t* sB = smem + 5120;        // [pl*128+row][k32 @40]
  const int tid = threadIdx.x, lane = tid & 63, wv = tid >> 6;
  const int l15 = lane & 15, q = lane >> 4;
  const int pxT = blockIdx.x, coT = blockIdx.y;
  f32x4 acc[4][2];
#pragma unroll
  for (int m = 0; m < 4; ++m)
#pragma unroll
    for (int n = 0; n < 2; ++n) acc[m][n] = (f32x4){0.f, 0.f, 0.f, 0.f};

  const int brow = tid & 127;
  const ushort_t* xb = (tid >> 7) ? x1 : x0;
  const size_t rowb = ((size_t)(pxT * 128 + brow)) << 8;

  for (int chunk = 0; chunk < 8; ++chunk) {
    uint4 bg[4], ag[2];
    const int koff = chunk * 32;
#pragma unroll
    for (int i = 0; i < 4; ++i) bg[i] = *(const uint4*)(xb + rowb + koff + i * 8);
    const ushort_t* ap = wp + ((size_t)(chunk * 4 + coT) << 12);  // [pl][64][32] = 4096
#pragma unroll
    for (int i = 0; i < 2; ++i) {
      int idx = tid + 256 * i;                 // 0..511
      ag[i] = *(const uint4*)(ap + (idx & 127) * 32 + (idx >> 7) * 8);
    }
    __syncthreads();
#pragma unroll
    for (int i = 0; i < 2; ++i) {
      int idx = tid + 256 * i;
      *(uint4*)(&sA[(idx & 127) * 40 + (idx >> 7) * 8]) = ag[i];
    }
#pragma unroll
    for (int i = 0; i < 4; ++i)
      *(uint4*)(&sB[tid * 40 + i * 8]) = bg[i];
    __syncthreads();
    short8 af[4][2], bf[2][2];
#pragma unroll
    for (int m = 0; m < 4; ++m)
#pragma unroll
      for (int pl = 0; pl < 2; ++pl)
        af[m][pl] = *(const short8*)(sA + (pl * 64 + m * 16 + l15) * 40 + q * 8);
#pragma unroll
    for (int n = 0; n < 2; ++n)
#pragma unroll
      for (int pl = 0; pl < 2; ++pl)
        bf[n][pl] = *(const short8*)(sB + (pl * 128 + wv * 32 + n * 16 + l15) * 40 + q * 8);
#pragma unroll
    for (int m = 0; m < 4; ++m)
#pragma unroll
      for (int n = 0; n < 2; ++n) {
        acc[m][n] = __builtin_amdgcn_mfma_f32_16x16x32_bf16(af[m][0], bf[n][0], acc[m][n], 0, 0, 0);
        acc[m][n] = __builtin_amdgcn_mfma_f32_16x16x32_bf16(af[m][0], bf[n][1], acc[m][n], 0, 0, 0);
        acc[m][n] = __builtin_amdgcn_mfma_f32_16x16x32_bf16(af[m][1], bf[n][0], acc[m][n], 0, 0, 0);
      }
  }
  __syncthreads();
  // epilogue: h += v (+bias); optionally split(relu(h)) via smem
#pragma unroll
  for (int m = 0; m < 4; ++m) {
#pragma unroll
    for (int n = 0; n < 2; ++n) {
#pragma unroll
      for (int r = 0; r < 4; ++r) {
        const int co_l = m * 16 + q * 4 + r;        // [0,64)
        const int px_l = wv * 32 + n * 16 + l15;    // [0,128)
        float v = acc[m][n][r] + bias[coT * 64 + co_l];
        const int px = pxT * 128 + px_l;
        const int img = px >> 10, pp = px & 1023;
        const size_t ha = ((size_t)(img * 256 + coT * 64 + co_l)) * 1024 + pp;
        v += h32[ha];
        h32[ha] = v;
        if (WS) {
          float sv = fmaxf(v, 0.f);
          ushort_t b0 = f2bf(sv);
          smem[px_l * 72 + co_l] = b0;
          smem[9216 + px_l * 72 + co_l] = f2bf(sv - bf2f(b0));
        }
      }
    }
  }
  if (WS) {
    __syncthreads();
#pragma unroll
    for (int i = 0; i < 8; ++i) {
      int idx = tid + 256 * i;
      int pl = idx >> 10, w2 = idx & 1023, pxl = w2 >> 3, g = w2 & 7;
      uint4 vv = *(const uint4*)(smem + pl * 9216 + pxl * 72 + g * 8);
      ushort_t* dst = (pl ? sp1 : sp0) + ((size_t)(pxT * 128 + pxl)) * 256 + coT * 64 + g * 8;
      *(uint4*)dst = vv;
    }
  }
}

// ---------- 1x1 conv fp32 (to_z only) ----------
__global__ __launch_bounds__(256) void k_conv1x1(
    const float* __restrict__ in, float* __restrict__ out,
    const float* __restrict__ wT, const float* __restrict__ bias,
    int CI, int CO, int P)
{
  const int p = blockIdx.x * 256 + threadIdx.x;
  const int cob = blockIdx.y * 16;
  const int n = blockIdx.z;
  const float* inN = in + (size_t)n * CI * P + p;
  float acc[16];
#pragma unroll
  for (int i = 0; i < 16; ++i) acc[i] = bias[cob + i];
  const float* wr = wT + cob;
#pragma unroll 4
  for (int ci = 0; ci < CI; ++ci) {
    float iv = inN[(size_t)ci * P];
    const float* w = wr + (size_t)ci * CO;  // uniform
#pragma unroll
    for (int i = 0; i < 16; ++i) acc[i] = fmaf(iv, w[i], acc[i]);
  }
  float* outN = out + (size_t)n * CO * P + p;
#pragma unroll
  for (int i = 0; i < 16; ++i) outN[(size_t)(cob + i) * P] = acc[i];
}

// ---------- VQ partial: 16 chunks of 32 codes ----------
__global__ __launch_bounds__(256) void k_vq_part(
    const float* __restrict__ z_e, const float* __restrict__ cb,
    const float* __restrict__ cnorm, float* __restrict__ pbest, int* __restrict__ pbid)
{
  int g = blockIdx.x * 256 + threadIdx.x;  // 8192 points
  int chunk = blockIdx.y;                  // 16 chunks
  int img = g >> 10, p = g & 1023;
  const float* zp = z_e + (size_t)img * 64 * 1024 + p;
  float z[64];
#pragma unroll
  for (int c = 0; c < 64; ++c) z[c] = zp[(size_t)c * 1024];
  float best = 3.4e38f; int bid = chunk << 5;
  const int j0 = chunk << 5;
  for (int j = j0; j < j0 + 32; ++j) {
    const float* cj = cb + j * 64;  // uniform -> scalar loads
    float m = 0.f;
#pragma unroll
    for (int c = 0; c < 64; ++c) m = fmaf(z[c], cj[c], m);
    float d = fmaf(-2.f, m, cnorm[j]);
    if (d < best) { best = d; bid = j; }  // strict <: first-min within chunk
  }
  pbest[chunk * 8192 + g] = best;
  pbid[chunk * 8192 + g] = bid;
}

// ---------- VQ reduce (ascending chunks -> np.argmin) + e_k gather ----------
__global__ __launch_bounds__(256) void k_vq_reduce(
    const float* __restrict__ pbest, const int* __restrict__ pbid,
    const float* __restrict__ cb, float* __restrict__ ids_f, float* __restrict__ ek)
{
  int g = blockIdx.x * 256 + threadIdx.x;  // 8192
  float best = 3.4e38f; int bid = 0;
#pragma unroll
  for (int ch = 0; ch < 16; ++ch) {
    float d = pbest[ch * 8192 + g];
    int b = pbid[ch * 8192 + g];
    if (d < best) { best = d; bid = b; }
  }
  ids_f[g] = (float)bid;
  int img = g >> 10, p = g & 1023;
  const float* cbid = cb + bid * 64;
  float* ekp = ek + (size_t)img * 64 * 1024 + p;
#pragma unroll
  for (int c = 0; c < 64; ++c) ekp[(size_t)c * 1024] = cbid[c];
}

// ---------- from_z 1x1 (64->256) + relu -> NHWC bf16 ----------
__global__ __launch_bounds__(256) void k_from_z(
    const float* __restrict__ ek, ushort_t* __restrict__ nhwc,
    const float* __restrict__ wT, const float* __restrict__ bias)
{
  const int p = blockIdx.x * 256 + threadIdx.x;  // 0..1023
  const int co0 = blockIdx.y * 16;
  const int n = blockIdx.z;
  const float* inN = ek + (size_t)n * 64 * 1024 + p;
  float acc[16];
#pragma unroll
  for (int i = 0; i < 16; ++i) acc[i] = bias[co0 + i];
#pragma unroll 4
  for (int ci = 0; ci < 64; ++ci) {
    float iv = inN[(size_t)ci * 1024];
    const float* w = wT + (size_t)ci * 256 + co0;  // uniform
#pragma unroll
    for (int i = 0; i < 16; ++i) acc[i] = fmaf(iv, w[i], acc[i]);
  }
  uint pk[8];
#pragma unroll
  for (int i = 0; i < 8; ++i) {
    ushort_t lo = f2bf(fmaxf(acc[2 * i], 0.f));
    ushort_t hi = f2bf(fmaxf(acc[2 * i + 1], 0.f));
    pk[i] = (uint)lo | ((uint)hi << 16);
  }
  ushort_t* op = nhwc + (((size_t)n * 1024 + p) * 256 + co0);
  uint4 v0; v0.x = pk[0]; v0.y = pk[1]; v0.z = pk[2]; v0.w = pk[3];
  uint4 v1; v1.x = pk[4]; v1.y = pk[5]; v1.z = pk[6]; v1.w = pk[7];
  *(uint4*)(op) = v0;
  *(uint4*)(op + 8) = v1;
}

// ---------- t1 convtranspose 4x4 s2 p1, 256->256, bf16 MFMA -> bf16 NHWC ----
__global__ __launch_bounds__(256) void k_mfma_t1(
    const ushort_t* __restrict__ nhwc, const ushort_t* __restrict__ wb,
    const float* __restrict__ bias, ushort_t* __restrict__ t1o)
{
  __shared__ ushort_t sA[128 * 40];
  __shared__ ushort_t sB[128 * 40];
  const int tid = threadIdx.x;
  const int lane = tid & 63;
  const int wv = tid >> 6;
  const int wm = wv & 1, wn = wv >> 1;
  const int l15 = lane & 15, q = lane >> 4;
  const int pxT = blockIdx.x, coT = blockIdx.y, par = blockIdx.z;
  const int ry = par & 1, rx = (par >> 1) & 1;
  const int pxbase = pxT * 128;
  const int img = pxbase >> 10;
  f32x4 acc[4][4];
#pragma unroll
  for (int i = 0; i < 4; ++i)
#pragma unroll
    for (int j = 0; j < 4; ++j) acc[i][j] = (f32x4){0.f, 0.f, 0.f, 0.f};

  for (int c = 0; c < 32; ++c) {
    const int tap = c >> 3, c8 = c & 7;
    const int a = tap >> 1, b = tap & 1;
    const ushort_t* Abase = wb + ((size_t)((par * 4 + tap) * 8 + c8) << 13);
    uint4 av[2], bvv[2];
#pragma unroll
    for (int r = 0; r < 2; ++r) {
      int idx = tid + 256 * r;             // 0..511
      int row = idx & 127, kg = idx >> 7;  // kg 0..3
      av[r] = *(const uint4*)(Abase + ((coT * 128 + row) * 32 + kg * 8));
      int px = pxbase + row;
      int u = (px >> 5) & 31, vv = px & 31;
      int iy = u + ry - a, ix = vv + rx - b;
      if ((unsigned)iy < 32u && (unsigned)ix < 32u)
        bvv[r] = *(const uint4*)(nhwc + ((size_t)(img * 1024 + iy * 32 + ix) * 256 + c8 * 32 + kg * 8));
      else { bvv[r].x = 0u; bvv[r].y = 0u; bvv[r].z = 0u; bvv[r].w = 0u; }
    }
    __syncthreads();
#pragma unroll
    for (int r = 0; r < 2; ++r) {
      int idx = tid + 256 * r;
      int row = idx & 127, kg = idx >> 7;
      *(uint4*)(&sA[row * 40 + kg * 8]) = av[r];
      *(uint4*)(&sB[row * 40 + kg * 8]) = bvv[r];
    }
    __syncthreads();
    short8 af[4], bfr[4];
#pragma unroll
    for (int i = 0; i < 4; ++i)
      af[i] = *(const short8*)(sA + (wm * 64 + i * 16 + l15) * 40 + q * 8);
#pragma unroll
    for (int j = 0; j < 4; ++j)
      bfr[j] = *(const short8*)(sB + (wn * 64 + j * 16 + l15) * 40 + q * 8);
#pragma unroll
    for (int i = 0; i < 4; ++i)
#pragma unroll
      for (int j = 0; j < 4; ++j)
        acc[i][j] = __builtin_amdgcn_mfma_f32_16x16x32_bf16(af[i], bfr[j], acc[i][j], 0, 0, 0);
  }
#pragma unroll
  for (int i = 0; i < 4; ++i) {
    int co = coT * 128 + wm * 64 + i * 16 + q * 4;
#pragma unroll
    for (int j = 0; j < 4; ++j) {
      int px = pxbase + wn * 64 + j * 16 + l15;
      int u = (px >> 5) & 31, vv = px & 31;
      int oy = 2 * u + ry, ox = 2 * vv + rx;
      ushort_t e0 = f2bf(fmaxf(acc[i][j][0] + bias[co + 0], 0.f));
      ushort_t e1 = f2bf(fmaxf(acc[i][j][1] + bias[co + 1], 0.f));
      ushort_t e2 = f2bf(fmaxf(acc[i][j][2] + bias[co + 2], 0.f));
      ushort_t e3 = f2bf(fmaxf(acc[i][j][3] + bias[co + 3], 0.f));
      uint2 pk; pk.x = (uint)e0 | ((uint)e1 << 16); pk.y = (uint)e2 | ((uint)e3 << 16);
      *(uint2*)(t1o + ((size_t)(img * 4096 + oy * 64 + ox) * 256 + co)) = pk;
    }
  }
}

// ---------- t2 convtranspose 4x4 s2 p1, 256->3, bf16 MFMA, sigmoid ----------
__global__ __launch_bounds__(256) void k_mfma_t2(
    const ushort_t* __restrict__ t1o, const ushort_t* __restrict__ wb,
    const float* __restrict__ bias, float* __restrict__ out)
{
  __shared__ ushort_t sA2[256 * 40];
  __shared__ ushort_t sB2[16 * 40];
  const int tid = threadIdx.x, lane = tid & 63, wv = tid >> 6;
  const int l15 = lane & 15, q = lane >> 4;
  const int pxb = blockIdx.x * 256;
  const int par = blockIdx.y;
  const int ry = par & 1, rx = (par >> 1) & 1;
  f32x4 acc[4];
#pragma unroll
  for (int m = 0; m < 4; ++m) acc[m] = (f32x4){0.f, 0.f, 0.f, 0.f};
  const int px = pxb + tid;
  const int pimg = px >> 12, pp = px & 4095, pu = pp >> 6, pv = pp & 63;
  size_t rb = 0; bool rv = false;
  for (int chunk = 0; chunk < 32; ++chunk) {
    const int tap = chunk >> 3, cg = chunk & 7;
    if ((chunk & 7) == 0) {
      const int a = tap >> 1, b = tap & 1;
      int iy = pu + ry - a, ix = pv + rx - b;
      rv = ((unsigned)iy < 64u) && ((unsigned)ix < 64u);
      rb = ((size_t)(pimg * 4096 + iy * 64 + ix)) << 8;
    }
    uint4 av[4];
#pragma unroll
    for (int kg = 0; kg < 4; ++kg) {
      if (rv) av[kg] = *(const uint4*)(t1o + rb + cg * 32 + kg * 8);
      else { av[kg].x = 0; av[kg].y = 0; av[kg].z = 0; av[kg].w = 0; }
    }
    uint4 bv;
    if (tid < 64) {
      int co = tid & 15, kgb = tid >> 4;
      bv = *(const uint4*)(wb + ((size_t)(par * 32 + chunk) * 16 + co) * 32 + kgb * 8);
    }
    __syncthreads();
#pragma unroll
    for (int kg = 0; kg < 4; ++kg)
      *(uint4*)(&sA2[tid * 40 + kg * 8]) = av[kg];
    if (tid < 64) {
      int co = tid & 15, kgb = tid >> 4;
      *(uint4*)(&sB2[co * 40 + kgb * 8]) = bv;
    }
    __syncthreads();
    short8 bf = *(const short8*)(sB2 + l15 * 40 + q * 8);
#pragma unroll
    for (int m = 0; m < 4; ++m) {
      short8 af = *(const short8*)(sA2 + (wv * 64 + m * 16 + l15) * 40 + q * 8);
      acc[m] = __builtin_amdgcn_mfma_f32_16x16x32_bf16(af, bf, acc[m], 0, 0, 0);
    }
    __syncthreads();
  }
  const int co = l15;
  if (co < 3) {
    float bco = bias[co];
#pragma unroll
    for (int m = 0; m < 4; ++m) {
#pragma unroll
      for (int r = 0; r < 4; ++r) {
        int opx = pxb + wv * 64 + m * 16 + q * 4 + r;
        int img = opx >> 12, p = opx & 4095, u = p >> 6, v = p & 63;
        size_t addr = ((size_t)(img * 3 + co)) * 16384 + (2 * u + ry) * 128 + (2 * v + rx);
        out[addr] = 1.f / (1.f + expf(-(acc[m][r] + bco)));
      }
    }
  }
}

// ---------------------------------------------------------------------------
extern "C" void kernel_launch(void* const* d_in, const int* in_sizes, int n_in,
                              void* d_out, int out_size, void* d_ws, size_t ws_size,
                              hipStream_t stream) {
  (void)in_sizes; (void)n_in; (void)out_size; (void)ws_size;
  const float* x      = (const float*)d_in[0];
  const float* c1_w   = (const float*)d_in[1];
  const float* c1_b   = (const float*)d_in[2];
  const float* c2_w   = (const float*)d_in[3];
  const float* c2_b   = (const float*)d_in[4];
  const float* r0_w3  = (const float*)d_in[5];
  const float* r0_b3  = (const float*)d_in[6];
  const float* r0_w1  = (const float*)d_in[7];
  const float* r0_b1  = (const float*)d_in[8];
  const float* r1_w3  = (const float*)d_in[9];
  const float* r1_b3  = (const float*)d_in[10];
  const float* r1_w1  = (const float*)d_in[11];
  const float* r1_b1  = (const float*)d_in[12];
  const float* to_z_w = (const float*)d_in[13];
  const float* to_z_b = (const float*)d_in[14];
  const float* cb     = (const float*)d_in[15];
  const float* from_z_w = (const float*)d_in[16];
  const float* from_z_b = (const float*)d_in[17];
  const float* t1_w   = (const float*)d_in[18];
  const float* t1_b   = (const float*)d_in[19];
  const float* t2_w   = (const float*)d_in[20];
  const float* t2_b   = (const float*)d_in[21];

  float* wsf = (float*)d_ws;
  // era-overlapped regions (float offsets):
  ushort_t* xs1p0 = (ushort_t*)(wsf + 0);        // conv1-era [0, 4.19M)
  ushort_t* xs1p1 = (ushort_t*)(wsf + 4194304);  // conv1-era [4.19M, 8.39M)
  ushort_t* spB0  = (ushort_t*)(wsf + 0);        // res-era   [0, 1.05M)
  ushort_t* spB1  = (ushort_t*)(wsf + 1048576);  // res-era   [1.05M, 2.1M)
  float*    pbest = wsf + 0;                     // vq-era
  int*      pbid  = (int*)(wsf + 131072);        // vq-era
  float*    slabC = wsf + 2097152;               // 3x3-era [2.1M, 4.19M)
  float*    slabD = wsf + 4194304;               // 3x3-era [4.19M, 6.29M)
  float*    slabE = wsf + 6291456;               // 3x3-era [6.29M, 8.39M)
  ushort_t* t1out = (ushort_t*)(wsf + 2097152);  // dec-era [2.1M, 6.29M)
  ushort_t* decn  = (ushort_t*)(wsf + 6291456);  // dec-era [6.29M, 7.34M)
  float*    h32   = wsf + 8388608;               // [8.39M, 10.49M); conv2 slabB (in-place)
  float*    slabA = wsf + 10485760;              // conv2-era; spA region ONLY after k_epi_sum_relu
  ushort_t* spA0  = (ushort_t*)(wsf + 10485760);
  ushort_t* spA1  = (ushort_t*)(wsf + 11534336);
  ushort_t* wp_c2   = (ushort_t*)(wsf + 12582912);
  ushort_t* wp_r0w3 = (ushort_t*)(wsf + 13631488);
  ushort_t* wp_r1w3 = (ushort_t*)(wsf + 14221312);
  ushort_t* wp_r0w1 = (ushort_t*)(wsf + 14811136);
  ushort_t* wp_r1w1 = (ushort_t*)(wsf + 14876672);
  float*    wt_c1   = wsf + 14942208;
  float*    wt_toz  = wsf + 14954496;
  float*    wt_fromz= wsf + 14970880;
  ushort_t* t1wb    = (ushort_t*)(wsf + 14987264);
  ushort_t* w2pk    = (ushort_t*)(wsf + 15511552);
  float*    cnorm   = wsf + 15544320;

  float* out_img = (float*)d_out;        // 393216
  float* z_e_out = out_img + 393216;     // 524288
  float* e_k_out = z_e_out + 524288;     // 524288
  float* ids_out = e_k_out + 524288;     // 8192 (stored as float)

  // ---- weight prep ----
  k_transpose_w<<<48, 256, 0, stream>>>(c1_w, wt_c1, 256, 48);
  k_transpose_w<<<64, 256, 0, stream>>>(to_z_w, wt_toz, 64, 256);
  k_transpose_w<<<64, 256, 0, stream>>>(from_z_w, wt_fromz, 256, 64);
  k_prep_enc<0><<<8192, 256, 0, stream>>>(c2_w,  wp_c2,   128 << 14);
  k_prep_enc<1><<<4608, 256, 0, stream>>>(r0_w3, wp_r0w3, 72 << 14);
  k_prep_enc<1><<<4608, 256, 0, stream>>>(r1_w3, wp_r1w3, 72 << 14);
  k_prep_enc<2><<<512,  256, 0, stream>>>(r0_w1, wp_r0w1, 8 << 14);
  k_prep_enc<2><<<512,  256, 0, stream>>>(r1_w1, wp_r1w1, 8 << 14);
  k_prep_t1w<<<4096, 256, 0, stream>>>(t1_w, t1wb);
  k_prep_t2w<<<256, 256, 0, stream>>>(t2_w, w2pk);
  k_prep_cb<<<2, 256, 0, stream>>>(cb, cnorm);

  // ---- encoder ----
  k_conv1_split<<<dim3(64, 4, 8), 256, 0, stream>>>(x, xs1p0, xs1p1, wt_c1, c1_b);
  // conv2: kz=2 -> slabA + slabB(=h32 region); epi1 consumes slabA FULLY,
  // then epi2 (split) may overwrite the slabA region with spA planes.
  k_enc_mfma_split<0, 2><<<dim3(64, 4, 2), 256, 0, stream>>>(
      xs1p0, xs1p1, wp_c2, slabA, h32, nullptr);
  k_epi_sum_relu<<<8192, 256, 0, stream>>>(slabA, h32, c2_b);
  k_split_h<<<dim3(32, 16), 256, 0, stream>>>(h32, spA0, spA1);
  // r0 w3: kz=3 -> slabC/D/E (dead conv1-output region); epi -> spB
  k_enc_mfma_split<1, 3><<<dim3(64, 4, 3), 256, 0, stream>>>(
      spA0, spA1, wp_r0w3, slabC, slabD, slabE);
  k_epi3<<<dim3(32, 16), 256, 0, stream>>>(slabC, slabD, slabE, r0_b3, spB0, spB1);
  // r0 w1: h += conv; write h32 + split(relu(h)) -> spA
  k_enc_1x1<true><<<dim3(64, 4), 256, 0, stream>>>(spB0, spB1, wp_r0w1, r0_b1, h32, spA0, spA1);
  // r1 w3: kz=3
  k_enc_mfma_split<1, 3><<<dim3(64, 4, 3), 256, 0, stream>>>(
      spA0, spA1, wp_r1w3, slabC, slabD, slabE);
  k_epi3<<<dim3(32, 16), 256, 0, stream>>>(slabC, slabD, slabE, r1_b3, spB0, spB1);
  // r1 w1: h += conv; write h32 only
  k_enc_1x1<false><<<dim3(64, 4), 256, 0, stream>>>(spB0, spB1, wp_r1w1, r1_b1, h32, nullptr, nullptr);
  // to_z (fp32)
  k_conv1x1<<<dim3(4, 4, 8), 256, 0, stream>>>(h32, z_e_out, wt_toz, to_z_b, 256, 64, 1024);

  // ---- VQ (chunk-parallel; bit-identical argmin) ----
  k_vq_part<<<dim3(32, 16), 256, 0, stream>>>(z_e_out, cb, cnorm, pbest, pbid);
  k_vq_reduce<<<32, 256, 0, stream>>>(pbest, pbid, cb, ids_out, e_k_out);

  // ---- decoder (bf16) ----
  k_from_z<<<dim3(4, 16, 8), 256, 0, stream>>>(e_k_out, decn, wt_fromz, from_z_b);
  k_mfma_t1<<<dim3(64, 2, 4), 256, 0, stream>>>(decn, t1wb, t1_b, t1out);
  k_mfma_t2<<<dim3(128, 4), 256, 0, stream>>>(t1out, w2pk, t2_b, out_img);
}